// Round 12
// baseline (207.565 us; speedup 1.0000x reference)
//
#include <hip/hip_runtime.h>

// MambaLayer bidirectional selective-scan (bf16 MFMA GEMMs, packed xc/dt scan,
// packed-fp32 state math, DUAL-CHUNK scans for in-wave ILP).
// Shapes: B=4, L=8192, d_model=128, d_inner=256, d_state=16, dt_rank=8.
#define NB   4
#define LSEQ 8192
#define DM   128
#define DI   256
#define NS   16
#define RK   8
#define NCH  256          // chunks over L
#define LC   32           // L / NCH
#define MTOT (NB*LSEQ)
#define LOG2E 1.44269504088896340736f
#define LN2f  0.69314718055994530942f

#if __has_builtin(__builtin_amdgcn_exp2f)
__device__ __forceinline__ float fexp2(float x){ return __builtin_amdgcn_exp2f(x); }
#else
__device__ __forceinline__ float fexp2(float x){ return exp2f(x); }
#endif
#if __has_builtin(__builtin_amdgcn_logf)
__device__ __forceinline__ float flog2(float x){ return __builtin_amdgcn_logf(x); }
#else
__device__ __forceinline__ float flog2(float x){ return log2f(x); }
#endif
#if __has_builtin(__builtin_amdgcn_rcpf)
__device__ __forceinline__ float frcp(float x){ return __builtin_amdgcn_rcpf(x); }
#else
__device__ __forceinline__ float frcp(float x){ return 1.f/x; }
#endif
__device__ __forceinline__ float fexpn(float x){ return fexp2(x*LOG2E); }
__device__ __forceinline__ float fsilu(float x){ return x*frcp(1.f + fexpn(-x)); }
__device__ __forceinline__ float fsoftplus(float x){
  return fmaxf(x,0.f) + flog2(1.f + fexpn(-fabsf(x)))*LN2f;
}

__device__ __forceinline__ unsigned short f2bf(float v){
  unsigned int u = __float_as_uint(v);
  return (unsigned short)((u + 0x7FFFu + ((u >> 16) & 1u)) >> 16);
}
__device__ __forceinline__ float bf2f(unsigned short h){
  return __uint_as_float(((unsigned int)h) << 16);
}

typedef __attribute__((ext_vector_type(8))) short bf16x8;
typedef __attribute__((ext_vector_type(4))) float f32x4;
typedef __attribute__((ext_vector_type(2))) float f32x2;

#if __has_builtin(__builtin_elementwise_fma)
__device__ __forceinline__ f32x2 pkfma(f32x2 a, f32x2 b, f32x2 c){ return __builtin_elementwise_fma(a,b,c); }
#else
__device__ __forceinline__ f32x2 pkfma(f32x2 a, f32x2 b, f32x2 c){ return a*b + c; }
#endif

// one scan step (local pass): update h2[8], accumulate sac
#define SCAN_STEP_L(uu, bcrow, h2, sac) do { \
  float xc_ = __uint_as_float((uu) << 16); \
  float dt_ = __uint_as_float((uu) & 0xffff0000u); \
  (sac) += dt_; \
  float dx_ = dt_*xc_; \
  const float4* bq_ = (const float4*)(bcrow); \
  float bcl_[16]; \
  *(float4*)(bcl_+0)=bq_[0]; *(float4*)(bcl_+4)=bq_[1]; \
  *(float4*)(bcl_+8)=bq_[2]; *(float4*)(bcl_+12)=bq_[3]; \
  const f32x2* bb2_ = (const f32x2*)bcl_; \
  f32x2 e2_[8]; \
  if (pw) { \
    float e1_=fexp2(a20*dt_); float es_=e1_*e1_; f32x2 esq_={es_,es_}; \
    e2_[0]=(f32x2){e1_,es_}; \
    _Pragma("unroll") for(int k_=1;k_<8;++k_) e2_[k_]=e2_[k_-1]*esq_; \
  } else { \
    _Pragma("unroll") for(int k_=0;k_<8;++k_) \
      e2_[k_]=(f32x2){fexp2(A2[2*k_]*dt_),fexp2(A2[2*k_+1]*dt_)}; \
  } \
  f32x2 dx2_={dx_,dx_}; \
  _Pragma("unroll") for(int k_=0;k_<8;++k_) (h2)[k_]=pkfma((h2)[k_],e2_[k_],bb2_[k_]*dx2_); \
} while(0)

// one scan step (output pass): update h2[8], emit s
#define SCAN_STEP_O(uu, bcrow, h2, zus, spp) do { \
  float xc_ = __uint_as_float((uu) << 16); \
  float dt_ = __uint_as_float((uu) & 0xffff0000u); \
  float dx_ = dt_*xc_; \
  const float4* bq_ = (const float4*)(bcrow); \
  float bcl_[32]; \
  *(float4*)(bcl_+0)=bq_[0];  *(float4*)(bcl_+4)=bq_[1]; \
  *(float4*)(bcl_+8)=bq_[2];  *(float4*)(bcl_+12)=bq_[3]; \
  *(float4*)(bcl_+16)=bq_[4]; *(float4*)(bcl_+20)=bq_[5]; \
  *(float4*)(bcl_+24)=bq_[6]; *(float4*)(bcl_+28)=bq_[7]; \
  const f32x2* bb2_ = (const f32x2*)bcl_; \
  const f32x2* cc2_ = (const f32x2*)(bcl_+16); \
  f32x2 e2_[8]; \
  if (pw) { \
    float e1_=fexp2(a20*dt_); float es_=e1_*e1_; f32x2 esq_={es_,es_}; \
    e2_[0]=(f32x2){e1_,es_}; \
    _Pragma("unroll") for(int k_=1;k_<8;++k_) e2_[k_]=e2_[k_-1]*esq_; \
  } else { \
    _Pragma("unroll") for(int k_=0;k_<8;++k_) \
      e2_[k_]=(f32x2){fexp2(A2[2*k_]*dt_),fexp2(A2[2*k_+1]*dt_)}; \
  } \
  f32x2 dx2_={dx_,dx_}; \
  f32x2 yv2_={0.f,0.f}; \
  _Pragma("unroll") for(int k_=0;k_<8;++k_) { \
    (h2)[k_]=pkfma((h2)[k_],e2_[k_],bb2_[k_]*dx2_); \
    yv2_=pkfma((h2)[k_],cc2_[k_],yv2_); \
  } \
  float yv_ = yv2_.x + yv2_.y; \
  yv_ = fmaf(xc_, Dd, yv_); \
  *(spp) = f2bf(yv_ * bf2f(zus)); \
} while(0)

// ---------------------------------------------------------------------------
// K0: weights -> bf16: in_proj [512][128]; x_proj padded [2][48][256];
// out_proj [128][256].
// ---------------------------------------------------------------------------
__global__ __launch_bounds__(256) void k_prep_w(
    const float* __restrict__ wip, unsigned short* __restrict__ wipbf,
    const float* __restrict__ xwf, const float* __restrict__ xwb, unsigned short* __restrict__ xwbf,
    const float* __restrict__ wop, unsigned short* __restrict__ wopbf)
{
  int i = blockIdx.x*256 + threadIdx.x;      // 0..122879
  if (i < 65536) {
    wipbf[i] = f2bf(wip[i]);
  } else if (i < 90112) {
    int j = i - 65536;                       // 0..24575
    int dirw = j / 12288;
    int rem = j - dirw*12288;
    int row = rem >> 8, k = rem & 255;
    const float* src = dirw ? xwb : xwf;
    xwbf[j] = (row < 40) ? f2bf(src[row*256 + k]) : (unsigned short)0;
  } else {
    int j = i - 90112;                       // 0..32767
    wopbf[j] = f2bf(wop[j]);
  }
}

// ---------------------------------------------------------------------------
// K1a: LN1 -> xn bf16 [MTOT][128]. Reads x [B,128,L] coalesced.
// ---------------------------------------------------------------------------
__global__ __launch_bounds__(256) void k_ln(
    const float* __restrict__ x, const float* __restrict__ ln1w, const float* __restrict__ ln1b,
    unsigned short* __restrict__ xnbf)
{
  __shared__ float a_s[DM][65];
  __shared__ float mS[64], rS[64];
  const int tid = threadIdx.x;
  const int m0 = blockIdx.x * 64;
  const int b = m0 >> 13, l0 = m0 & (LSEQ-1);
  const float* xb = x + b*DM*LSEQ;
#pragma unroll
  for (int i = 0; i < 32; ++i) {
    int idx = tid + i*256;
    int d = idx >> 6, l = idx & 63;
    a_s[d][l] = xb[d*LSEQ + l0 + l];
  }
  __syncthreads();
  {
    int p = tid & 3, l = tid >> 2;
    float s = 0.f, q = 0.f;
#pragma unroll
    for (int jj = 0; jj < 32; ++jj) {
      float v = a_s[p + 4*jj][l];
      s += v; q += v*v;
    }
    s += __shfl_xor(s,1); s += __shfl_xor(s,2);
    q += __shfl_xor(q,1); q += __shfl_xor(q,2);
    float m = s*(1.f/DM);
    float var = q*(1.f/DM) - m*m;
    if (p == 0) { mS[l] = m; rS[l] = rsqrtf(var + 1e-5f); }
  }
  __syncthreads();
#pragma unroll
  for (int i = 0; i < 32; ++i) {
    int idx = tid + i*256;
    int l = idx >> 7, d = idx & 127;
    float v = (a_s[d][l] - mS[l])*rS[l]*ln1w[d] + ln1b[d];
    xnbf[(m0+l)*DM + d] = f2bf(v);
  }
}

// ---------------------------------------------------------------------------
// K1b: in_proj GEMM via bf16 MFMA (single plane). Tile 64x64, K=128.
// n0<256 -> xib (bf16); n0>=256 -> zzb = silu(z) bf16.
// ---------------------------------------------------------------------------
__global__ __launch_bounds__(256) void k_gemm_in(
    const unsigned short* __restrict__ xnbf, const unsigned short* __restrict__ wipbf,
    unsigned short* __restrict__ xib, unsigned short* __restrict__ zzb)
{
  __shared__ char lds[32768];                 // 2 planes x 16KB (64 rows x 128 bf16)
  const int tid = threadIdx.x;
  const int m0 = blockIdx.x * 64;
  const int n0 = blockIdx.y * 64;
  const unsigned short* srcs[2] = { xnbf + m0*DM, wipbf + n0*DM };
#pragma unroll
  for (int p = 0; p < 2; ++p) {
#pragma unroll
    for (int i = 0; i < 4; ++i) {
      int u = tid + i*256;                    // 16B unit within plane
      int row = u >> 4, c = u & 15;
      int dstu = p*1024 + row*16 + (c ^ (row & 7));
      *(uint4*)(lds + dstu*16) = *(const uint4*)(srcs[p] + row*DM + c*8);
    }
  }
  __syncthreads();
  const int wid = tid >> 6, lane = tid & 63;
  const int m0w = (wid & 1)*32, n0w = (wid >> 1)*32;
  const int lr = lane & 15, kg = lane >> 4;
  bf16x8 af[2][4], bfv[2][4];
#pragma unroll
  for (int mi = 0; mi < 2; ++mi) {
    int row = m0w + mi*16 + lr;
#pragma unroll
    for (int kk = 0; kk < 4; ++kk) {
      int slot = (kk*4 + kg) ^ (row & 7);
      af[mi][kk] = *(const bf16x8*)(lds + row*256 + slot*16);
    }
  }
#pragma unroll
  for (int nj = 0; nj < 2; ++nj) {
    int row = n0w + nj*16 + lr;
#pragma unroll
    for (int kk = 0; kk < 4; ++kk) {
      int slot = (kk*4 + kg) ^ (row & 7);
      bfv[nj][kk] = *(const bf16x8*)(lds + 16384 + row*256 + slot*16);
    }
  }
  f32x4 acc[2][2];
#pragma unroll
  for (int mi = 0; mi < 2; ++mi)
#pragma unroll
    for (int nj = 0; nj < 2; ++nj) acc[mi][nj] = 0.f;
#pragma unroll
  for (int kk = 0; kk < 4; ++kk)
#pragma unroll
    for (int mi = 0; mi < 2; ++mi)
#pragma unroll
      for (int nj = 0; nj < 2; ++nj)
        acc[mi][nj] = __builtin_amdgcn_mfma_f32_16x16x32_bf16(af[mi][kk], bfv[nj][kk], acc[mi][nj], 0,0,0);
  // C/D: col = lane&15 (n), row = (lane>>4)*4 + r (m)
  if (n0 < 256) {
#pragma unroll
    for (int mi = 0; mi < 2; ++mi)
#pragma unroll
      for (int nj = 0; nj < 2; ++nj) {
        int n_g = n0 + n0w + nj*16 + lr;
#pragma unroll
        for (int r = 0; r < 4; ++r) {
          int m_g = m0 + m0w + mi*16 + kg*4 + r;
          xib[(size_t)m_g*DI + n_g] = f2bf(acc[mi][nj][r]);
        }
      }
  } else {
#pragma unroll
    for (int mi = 0; mi < 2; ++mi)
#pragma unroll
      for (int nj = 0; nj < 2; ++nj) {
        int n_g = (n0 - 256) + n0w + nj*16 + lr;
#pragma unroll
        for (int r = 0; r < 4; ++r) {
          int m_g = m0 + m0w + mi*16 + kg*4 + r;
          zzb[(size_t)m_g*DI + n_g] = f2bf(fsilu(acc[mi][nj][r]));
        }
      }
  }
}

// ---------------------------------------------------------------------------
// K2: conv4+SiLU -> xc into LDS A-plane (phase1); x_proj MFMA (phase2,
// dt_r -> LDS, B/C -> interleaved BC[row][32] global); phase3: dt, xc|dt
// packed into uint4 GROUPS of 4 steps: xdt[db][l/4][d][4] (coalesced 16B).
// ---------------------------------------------------------------------------
__global__ __launch_bounds__(256) void k_conv_xproj(
  const unsigned short* __restrict__ xib,
  const float* __restrict__ cwf, const float* __restrict__ cbf,
  const float* __restrict__ cwb, const float* __restrict__ cbb,
  const unsigned short* __restrict__ xwbf,   // [2][48][256] bf16
  const float* __restrict__ dtwf, const float* __restrict__ dtbf,
  const float* __restrict__ dtwb, const float* __restrict__ dtbb,
  float* __restrict__ BC,
  uint4* __restrict__ xdt4)
{
  __shared__ char lds[57344];   // A: 64x512B @0; W: 48x512B @32768
  __shared__ float dtr_s[64][8];
  const int tid = threadIdx.x, bid = blockIdx.x;
  const int lt = bid & (LSEQ/64 - 1);
  const int b  = (bid >> 7) & 3;
  const int dir = bid >> 9;
  const int l0 = lt*64;
  const int db = dir*NB + b;
  const unsigned short* xwp = xwbf + dir*48*256;
#pragma unroll
  for (int i = 0; i < 6; ++i) {
    int u = tid + i*256;
    int row = u >> 5, s = u & 31;
    *(uint4*)(lds + 32768 + row*512 + ((s ^ (row & 7))<<4)) =
        *(const uint4*)(xwp + row*256 + s*8);
  }
  const float* cw  = dir ? cwb : cwf;
  const float* cbp = dir ? cbb : cbf;
  const int d = tid;
  const float w0 = cw[d*4+0], w1 = cw[d*4+1], w2 = cw[d*4+2], w3 = cw[d*4+3];
  const float bias = cbp[d];
  const int g0 = dir ? (LSEQ-1-l0) : l0;
  const int stp = dir ? -DI : DI;
  const unsigned short* xp = xib + (size_t)(b*LSEQ)*DI + d + (size_t)g0*DI;
  float h3 = 0.f, h2 = 0.f, h1 = 0.f;
  if (l0 >= 3) { h3 = bf2f(xp[-3*stp]); h2 = bf2f(xp[-2*stp]); h1 = bf2f(xp[-1*stp]); }
  float r0 = bf2f(xp[0]), r1 = bf2f(xp[stp]), r2 = bf2f(xp[2*stp]), r3 = bf2f(xp[3*stp]);
  for (int j = 0; j < 64; j += 4) {
    float v0 = r0, v1 = r1, v2 = r2, v3 = r3;
    if (j + 4 < 64) {
      const unsigned short* q = xp + (j+4)*stp;
      r0 = bf2f(q[0]); r1 = bf2f(q[stp]); r2 = bf2f(q[2*stp]); r3 = bf2f(q[3*stp]);
    }
#pragma unroll
    for (int u = 0; u < 4; ++u) {
      float vv = (u==0)?v0:(u==1)?v1:(u==2)?v2:v3;
      float a = bias + w0*h3 + w1*h2 + w2*h1 + w3*vv;
      int row = j + u;
      *(unsigned short*)(lds + row*512 + ((((d>>3) ^ (row&7))<<4) + ((d&7)<<1))) = f2bf(fsilu(a));
      h3 = h2; h2 = h1; h1 = vv;
    }
  }
  __syncthreads();
  // ---- phase 2: MFMA [64 rows] x [48 cols], K=256 ----
  const int wid = tid >> 6, lane = tid & 63;
  const int lr = lane & 15, kg = lane >> 4;
  const int arow = wid*16 + lr;
  f32x4 acc[3];
#pragma unroll
  for (int j = 0; j < 3; ++j) acc[j] = 0.f;
#pragma unroll
  for (int t = 0; t < 8; ++t) {
    bf16x8 afv = *(const bf16x8*)(lds + arow*512 + (((t*4+kg) ^ (arow&7))<<4));
#pragma unroll
    for (int j = 0; j < 3; ++j) {
      int wrow = j*16 + lr;
      bf16x8 bfr = *(const bf16x8*)(lds + 32768 + wrow*512 + (((t*4+kg) ^ (wrow&7))<<4));
      acc[j] = __builtin_amdgcn_mfma_f32_16x16x32_bf16(afv, bfr, acc[j], 0,0,0);
    }
  }
  const int base_l = (db*LSEQ + l0) + wid*16 + kg*4;
  const int rloc = wid*16 + kg*4;
#pragma unroll
  for (int j = 0; j < 3; ++j) {
    int col = j*16 + lr;
#pragma unroll
    for (int r = 0; r < 4; ++r) {
      float v = acc[j][r];
      if (col < 8)       dtr_s[rloc + r][col] = v;
      else if (col < 40) BC[(size_t)(base_l + r)*32 + (col - 8)] = v;   // B:0..15, C:16..31
    }
  }
  __syncthreads();
  // ---- phase 3: dt = softplus(dtr @ dtw[d] + b[d]); pack xc|dt; write
  // uint4 per 4 rows: xdt4[(db*(LSEQ/4) + (l0+row)/4)*DI + d].
  const float* dtw = dir ? dtwb : dtwf;
  const float* dtbp= dir ? dtbb : dtbf;
  float dwv[8];
  *(float4*)(dwv+0) = *(const float4*)&dtw[d*RK];
  *(float4*)(dwv+4) = *(const float4*)&dtw[d*RK+4];
  const float dtbv = dtbp[d];
  uint4* xdtp = xdt4 + (size_t)(db*(LSEQ/4) + (l0>>2))*DI + d;
  unsigned int a4[4];
  for (int row = 0; row < 64; ++row) {
    float sd = dtbv;
#pragma unroll
    for (int r = 0; r < RK; ++r) sd = fmaf(dtr_s[row][r], dwv[r], sd);
    unsigned short dtb = f2bf(fsoftplus(sd));
    unsigned short xcb = *(const unsigned short*)(lds + row*512 + ((((d>>3) ^ (row&7))<<4) + ((d&7)<<1)));
    a4[row & 3] = (unsigned int)xcb | ((unsigned int)dtb << 16);
    if ((row & 3) == 3)
      xdtp[(size_t)(row >> 2)*DI] = make_uint4(a4[0], a4[1], a4[2], a4[3]);
  }
}

// ---------------------------------------------------------------------------
// K3: DUAL-CHUNK chunk-local scan: each block owns chunks (2p, 2p+1); the two
// independent recurrences interleave per step to fill dependency bubbles.
// ---------------------------------------------------------------------------
__global__ __launch_bounds__(256) void k_scan_local(
  const uint4* __restrict__ xdt4, const float* __restrict__ BC,
  const float* __restrict__ alogf, const float* __restrict__ alogb,
  unsigned short* __restrict__ hloc, float* __restrict__ sumdt)
{
  const int tid = threadIdx.x, bid = blockIdx.x;   // grid 1024
  const int p = bid & (NCH/2 - 1), b = (bid>>7)&3, dir = bid>>9;
  const int db = dir*NB + b;
  const int c0 = 2*p, c1 = 2*p+1;
  const int l0A = c0*LC, l0B = c1*LC;
  const float* alog = dir ? alogb : alogf;
  const int d = tid;
  float A2[NS];
#pragma unroll
  for (int n = 0; n < NS; ++n) A2[n] = -fexpn(alog[d*NS+n]) * LOG2E;
  const float a20 = A2[0];
  bool pw = true;
#pragma unroll
  for (int n = 1; n < NS; ++n) pw = pw && (fabsf(A2[n] - (n+1)*a20) <= 1e-3f*fabsf(A2[n]));
  f32x2 hA[8], hB[8];
#pragma unroll
  for (int k = 0; k < 8; ++k) { hA[k] = 0.f; hB[k] = 0.f; }
  const uint4* xqA = xdt4 + (size_t)(db*(LSEQ/4) + (l0A>>2))*DI + d;
  const uint4* xqB = xdt4 + (size_t)(db*(LSEQ/4) + (l0B>>2))*DI + d;
  const float* BCA = BC + (size_t)(db*LSEQ + l0A)*32;
  const float* BCB = BC + (size_t)(db*LSEQ + l0B)*32;
  uint4 XA = xqA[0], XB = xqB[0];
  float sacA = 0.f, sacB = 0.f;
  for (int g = 0; g < 8; ++g) {
    uint4 curA = XA, curB = XB;
    if (g + 1 < 8) { XA = xqA[(size_t)(g+1)*DI]; XB = xqB[(size_t)(g+1)*DI]; }
    unsigned int usA[4] = {curA.x, curA.y, curA.z, curA.w};
    unsigned int usB[4] = {curB.x, curB.y, curB.z, curB.w};
#pragma unroll
    for (int u = 0; u < 4; ++u) {
      SCAN_STEP_L(usA[u], BCA + (size_t)(g*4+u)*32, hA, sacA);
      SCAN_STEP_L(usB[u], BCB + (size_t)(g*4+u)*32, hB, sacB);
    }
  }
  unsigned int hp8[8];
#pragma unroll
  for (int k = 0; k < 8; ++k)
    hp8[k] = (unsigned int)f2bf(hA[k].x) | ((unsigned int)f2bf(hA[k].y) << 16);
  unsigned short* dstA = hloc + ((size_t)(db*NCH + c0)*DI + d)*NS;
  *(uint4*)(dstA)   = *(uint4*)(hp8);
  *(uint4*)(dstA+8) = *(uint4*)(hp8+4);
#pragma unroll
  for (int k = 0; k < 8; ++k)
    hp8[k] = (unsigned int)f2bf(hB[k].x) | ((unsigned int)f2bf(hB[k].y) << 16);
  unsigned short* dstB = hloc + ((size_t)(db*NCH + c1)*DI + d)*NS;
  *(uint4*)(dstB)   = *(uint4*)(hp8);
  *(uint4*)(dstB+8) = *(uint4*)(hp8+4);
  sumdt[(size_t)(db*NCH + c0)*DI + d] = sacA;
  sumdt[(size_t)(db*NCH + c1)*DI + d] = sacB;
}

// ---------------------------------------------------------------------------
// K4: sequential prefix over chunks (bf16 h, fp32 carry), 16-deep prefetch,
// IN-PLACE: hloc[c] becomes h_in[c].
// ---------------------------------------------------------------------------
__global__ __launch_bounds__(64) void k_prefix(
  unsigned short* __restrict__ hloc, const float* __restrict__ sumdt,
  const float* __restrict__ alogf, const float* __restrict__ alogb)
{
  const int gid = blockIdx.x*64 + threadIdx.x;   // 32768
  const int n = gid & 15;
  const int d = (gid >> 4) & 255;
  const int db = gid >> 12;
  const float* alog = (db >= NB) ? alogb : alogf;
  const float a2 = -fexpn(alog[d*NS+n]) * LOG2E;
  const int HS = DI*NS;                          // per-chunk stride (ushorts)
  unsigned short* hp = hloc + (size_t)db*NCH*HS + d*NS + n;
  const float* sp = sumdt + (size_t)db*NCH*DI + d;
  float hr = 0.f;
  float bl[16], bs[16];
#pragma unroll
  for (int j = 0; j < 16; ++j) { bl[j] = bf2f(hp[(size_t)j*HS]); bs[j] = sp[(size_t)j*DI]; }
  for (int blk = 0; blk < NCH/16; ++blk) {
    float nl[16], nsv[16];
    if (blk < NCH/16 - 1) {
#pragma unroll
      for (int j = 0; j < 16; ++j) {
        nl[j]  = bf2f(hp[(size_t)(blk*16+16+j)*HS]);
        nsv[j] = sp[(size_t)(blk*16+16+j)*DI];
      }
    }
#pragma unroll
    for (int j = 0; j < 16; ++j) {
      float hl = bl[j];
      hp[(size_t)(blk*16+j)*HS] = f2bf(hr);
      hr = fmaf(fexp2(a2*bs[j]), hr, hl);
    }
    if (blk < NCH/16 - 1) {
#pragma unroll
      for (int j = 0; j < 16; ++j) { bl[j] = nl[j]; bs[j] = nsv[j]; }
    }
  }
}

// ---------------------------------------------------------------------------
// K5: DUAL-CHUNK rescan from h_in producing y, + D-skip, * pre-silu'd z -> s.
// ---------------------------------------------------------------------------
__global__ __launch_bounds__(256) void k_scan_out(
  const uint4* __restrict__ xdt4, const unsigned short* __restrict__ zzb,
  const float* __restrict__ BC,
  const unsigned short* __restrict__ hinb,
  const float* __restrict__ alogf, const float* __restrict__ alogb,
  const float* __restrict__ Dskf, const float* __restrict__ Dskb,
  unsigned short* __restrict__ s2bf)
{
  const int tid = threadIdx.x, bid = blockIdx.x;   // grid 1024
  const int p = bid & (NCH/2 - 1), b = (bid>>7)&3, dir = bid>>9;
  const int db = dir*NB + b;
  const int c0 = 2*p, c1 = 2*p+1;
  const int l0A = c0*LC, l0B = c1*LC;
  const float* alog = dir ? alogb : alogf;
  const int d = tid;
  const float Dd = (dir ? Dskb : Dskf)[d];
  float A2[NS];
#pragma unroll
  for (int n = 0; n < NS; ++n) A2[n] = -fexpn(alog[d*NS+n]) * LOG2E;
  const float a20 = A2[0];
  bool pw = true;
#pragma unroll
  for (int n = 1; n < NS; ++n) pw = pw && (fabsf(A2[n] - (n+1)*a20) <= 1e-3f*fabsf(A2[n]));
  // h_in (bf16 -> fp32), both chunks
  f32x2 hA[8], hB[8];
  {
    const unsigned short* hbA = hinb + ((size_t)(db*NCH + c0)*DI + d)*NS;
    const unsigned short* hbB = hinb + ((size_t)(db*NCH + c1)*DI + d)*NS;
    uint4 p0 = *(const uint4*)(hbA);
    uint4 p1 = *(const uint4*)(hbA+8);
    unsigned int w[8] = {p0.x,p0.y,p0.z,p0.w,p1.x,p1.y,p1.z,p1.w};
#pragma unroll
    for (int k = 0; k < 8; ++k)
      hA[k] = (f32x2){__uint_as_float(w[k] << 16), __uint_as_float(w[k] & 0xffff0000u)};
    p0 = *(const uint4*)(hbB);
    p1 = *(const uint4*)(hbB+8);
    unsigned int w2[8] = {p0.x,p0.y,p0.z,p0.w,p1.x,p1.y,p1.z,p1.w};
#pragma unroll
    for (int k = 0; k < 8; ++k)
      hB[k] = (f32x2){__uint_as_float(w2[k] << 16), __uint_as_float(w2[k] & 0xffff0000u)};
  }
  const int stp = dir ? -DI : DI;
  const int g0A = dir ? (LSEQ-1-l0A) : l0A;
  const int g0B = dir ? (LSEQ-1-l0B) : l0B;
  const uint4* xqA = xdt4 + (size_t)(db*(LSEQ/4) + (l0A>>2))*DI + d;
  const uint4* xqB = xdt4 + (size_t)(db*(LSEQ/4) + (l0B>>2))*DI + d;
  const float* BCA = BC + (size_t)(db*LSEQ + l0A)*32;
  const float* BCB = BC + (size_t)(db*LSEQ + l0B)*32;
  const unsigned short* zpA = zzb + (size_t)(b*LSEQ + g0A)*DI + d;
  const unsigned short* zpB = zzb + (size_t)(b*LSEQ + g0B)*DI + d;
  unsigned short* spA = s2bf + (size_t)(db*LSEQ + l0A)*DI + d;
  unsigned short* spB = s2bf + (size_t)(db*LSEQ + l0B)*DI + d;
  uint4 XA = xqA[0], XB = xqB[0];
  for (int g = 0; g < 8; ++g) {
    uint4 curA = XA, curB = XB;
    if (g + 1 < 8) { XA = xqA[(size_t)(g+1)*DI]; XB = xqB[(size_t)(g+1)*DI]; }
    unsigned short zcA[4], zcB[4];
#pragma unroll
    for (int k = 0; k < 4; ++k) { zcA[k] = zpA[(g*4+k)*stp]; zcB[k] = zpB[(g*4+k)*stp]; }
    unsigned int usA[4] = {curA.x, curA.y, curA.z, curA.w};
    unsigned int usB[4] = {curB.x, curB.y, curB.z, curB.w};
#pragma unroll
    for (int u = 0; u < 4; ++u) {
      SCAN_STEP_O(usA[u], BCA + (size_t)(g*4+u)*32, hA, zcA[u], spA + (size_t)(g*4+u)*DI);
      SCAN_STEP_O(usB[u], BCB + (size_t)(g*4+u)*32, hB, zcB[u], spB + (size_t)(g*4+u)*DI);
    }
  }
}

// ---------------------------------------------------------------------------
// K6: MFMA out_proj. (sF + rev(sB)) @ W^T == [sF | rev(sB)] @ [W;W]^T.
// Epilogue: +residual, LN2, transposed store.
// ---------------------------------------------------------------------------
__global__ __launch_bounds__(512) void k_out(
  const unsigned short* __restrict__ s2bf,  // [2][NB][LSEQ][DI] bf16
  const unsigned short* __restrict__ wopbf, // [DM][DI] bf16
  const float* __restrict__ x, const float* __restrict__ ln2w, const float* __restrict__ ln2b,
  float* __restrict__ out)
{
  __shared__ char lds[65536];
  const int tid = threadIdx.x;
  const int m0 = blockIdx.x*64;
  const int b = m0 >> 13, l0 = m0 & (LSEQ-1);
  const unsigned short* sF = s2bf + (size_t)b*LSEQ*DI;
  const unsigned short* sB = s2bf + (size_t)(NB + b)*LSEQ*DI;
#pragma unroll
  for (int i = 0; i < 8; ++i) {
    int u = tid + i*512;
    int row = u >> 6, c = u & 63;
    int l = l0 + row;
    const unsigned short* src = (c < 32) ? (sF + (size_t)l*DI + c*8)
                                         : (sB + (size_t)(LSEQ-1-l)*DI + (c-32)*8);
    *(uint4*)(lds + row*1024 + ((c ^ (row & 7))<<4)) = *(const uint4*)src;
  }
  const int wid = tid >> 6;
  const int wr = wid >> 2, wc = wid & 3;
  const int lane = tid & 63, lr = lane & 15, kg = lane >> 4;
  bf16x8 wf[2][8];
#pragma unroll
  for (int nt = 0; nt < 2; ++nt) {
    int n = wc*32 + nt*16 + lr;
#pragma unroll
    for (int kt = 0; kt < 8; ++kt)
      wf[nt][kt] = *(const bf16x8*)(wopbf + n*DI + kt*32 + kg*8);
  }
  __syncthreads();
  f32x4 acc[2][2];
#pragma unroll
  for (int mt = 0; mt < 2; ++mt)
#pragma unroll
    for (int nt = 0; nt < 2; ++nt) acc[mt][nt] = 0.f;
#pragma unroll
  for (int kt2 = 0; kt2 < 16; ++kt2) {
#pragma unroll
    for (int mt = 0; mt < 2; ++mt) {
      int row = wr*32 + mt*16 + lr;
      int slot = (kt2*4 + kg) ^ (row & 7);
      bf16x8 af = *(const bf16x8*)(lds + row*1024 + (slot<<4));
#pragma unroll
      for (int nt = 0; nt < 2; ++nt)
        acc[mt][nt] = __builtin_amdgcn_mfma_f32_16x16x32_bf16(af, wf[nt][kt2 & 7], acc[mt][nt], 0,0,0);
    }
  }
  __syncthreads();
  float* smem = (float*)lds;
  const int RP = 133;
  float* mS = smem + 64*RP;
  float* rS = mS + 64;
  const float* xb = x + b*DM*LSEQ + l0;
#pragma unroll
  for (int mt = 0; mt < 2; ++mt) {
    int mbase = wr*32 + mt*16 + kg*4;
#pragma unroll
    for (int nt = 0; nt < 2; ++nt) {
      int n = wc*32 + nt*16 + lr;
      float4 rx = *(const float4*)&xb[n*LSEQ + mbase];
      smem[(mbase+0)*RP + n] = acc[mt][nt][0] + rx.x;
      smem[(mbase+1)*RP + n] = acc[mt][nt][1] + rx.y;
      smem[(mbase+2)*RP + n] = acc[mt][nt][2] + rx.z;
      smem[(mbase+3)*RP + n] = acc[mt][nt][3] + rx.w;
    }
  }
  __syncthreads();
  {
    int row = tid >> 3, p = tid & 7;
    float s = 0.f, q = 0.f;
#pragma unroll
    for (int jj = 0; jj < 16; ++jj) {
      float v = smem[row*RP + p*16 + jj];
      s += v; q += v*v;
    }
    s += __shfl_xor(s,1); s += __shfl_xor(s,2); s += __shfl_xor(s,4);
    q += __shfl_xor(q,1); q += __shfl_xor(q,2); q += __shfl_xor(q,4);
    if (p == 0) {
      float m = s*(1.f/DM);
      float var = q*(1.f/DM) - m*m;
      mS[row] = m; rS[row] = rsqrtf(var + 1e-5f);
    }
  }
  __syncthreads();
  float* ob = out + b*DM*LSEQ + l0;
#pragma unroll
  for (int i = 0; i < 16; ++i) {
    int idx = tid + i*512;
    int col = idx >> 6, l = idx & 63;
    float v = (smem[l*RP + col] - mS[l])*rS[l]*ln2w[col] + ln2b[col];
    ob[col*LSEQ + l] = v;
  }
}

// ---------------------------------------------------------------------------
extern "C" void kernel_launch(void* const* d_in, const int* in_sizes, int n_in,
                              void* d_out, int out_size, void* d_ws, size_t ws_size,
                              hipStream_t stream)
{
  (void)in_sizes; (void)n_in; (void)out_size; (void)ws_size;
  const float* x     = (const float*)d_in[0];
  const float* ln1w  = (const float*)d_in[1];
  const float* ln1b  = (const float*)d_in[2];
  const float* ln2w  = (const float*)d_in[3];
  const float* ln2b  = (const float*)d_in[4];
  const float* wip   = (const float*)d_in[5];
  const float* wop   = (const float*)d_in[6];
  const float* cwf   = (const float*)d_in[7];
  const float* cbf   = (const float*)d_in[8];
  const float* xwf   = (const float*)d_in[9];
  const float* dtwf  = (const float*)d_in[10];
  const float* dtbf  = (const float*)d_in[11];
  const float* alogf = (const float*)d_in[12];
  const float* Dskf  = (const float*)d_in[13];
  const float* cwb   = (const float*)d_in[14];
  const float* cbb   = (const float*)d_in[15];
  const float* xwb   = (const float*)d_in[16];
  const float* dtwb  = (const float*)d_in[17];
  const float* dtbb  = (const float*)d_in[18];
  const float* alogb = (const float*)d_in[19];
  const float* Dskb  = (const float*)d_in[20];

  // workspace layout (float units)
  float* ws    = (float*)d_ws;
  float* xibF  = ws;                    //  4,194,304 (xib: 8.4M ushort)
  float* zzbF  = xibF  + 4194304;       //  4,194,304 (zzb: 8.4M ushort)
  float* BC    = zzbF  + 4194304;       //  2,097,152 + pad (interleaved B|C)
  float* s2F   = BC    + 2097184;       //  8,388,608 (s2bf: 16.8M ushort)
  float* xdtF  = s2F   + 8388608;       // 16,777,216 (uint4-grouped xc|dt)
  float* hlocF = xdtF  + 16777216;      //  4,194,304 (bf16: 8.4M ushort)
  float* sumdt = hlocF + 4194304;       //    524,288
  float* xwbfF = sumdt + 524288;        //     12,288 (24,576 bf16)
  float* wopbfF= xwbfF + 12288;         //     16,384 (32,768 bf16)
  float* out   = (float*)d_out;
  // aliases in s2F region (fully rewritten by k_scan_out each call):
  unsigned short* xnbf  = (unsigned short*)s2F;             // 4,194,304 ush
  unsigned short* wipbf = (unsigned short*)(s2F + 2097152); //    65,536 ush
  unsigned short* s2bf  = (unsigned short*)s2F;
  unsigned short* xib   = (unsigned short*)xibF;
  unsigned short* zzb   = (unsigned short*)zzbF;
  uint4*          xdt4  = (uint4*)xdtF;
  unsigned short* hloc  = (unsigned short*)hlocF;
  unsigned short* xwbf  = (unsigned short*)xwbfF;
  unsigned short* wopbf = (unsigned short*)wopbfF;

  k_prep_w<<<480, 256, 0, stream>>>(wip, wipbf, xwf, xwb, xwbf, wop, wopbf);
  k_ln<<<512, 256, 0, stream>>>(x, ln1w, ln1b, xnbf);
  k_gemm_in<<<dim3(512,8), 256, 0, stream>>>(xnbf, wipbf, xib, zzb);
  k_conv_xproj<<<1024, 256, 0, stream>>>(xib, cwf,cbf,cwb,cbb, xwbf,
                                         dtwf,dtbf,dtwb,dtbb, BC, xdt4);
  k_scan_local<<<1024, 256, 0, stream>>>(xdt4, BC, alogf, alogb, hloc, sumdt);
  k_prefix<<<512, 64, 0, stream>>>(hloc, sumdt, alogf, alogb);
  k_scan_out<<<1024, 256, 0, stream>>>(xdt4, zzb, BC, hloc,
                                       alogf, alogb, Dskf, Dskb, s2bf);
  k_out<<<512, 512, 0, stream>>>(s2bf, wopbf, x, ln2w, ln2b, out);
}

// Round 13
// 181.470 us; speedup vs baseline: 1.1438x; 1.1438x over previous
//
#include <hip/hip_runtime.h>

// MambaLayer bidirectional selective-scan.
// bf16 MFMA GEMMs; ONE serial scan pass (y_local + cumdt packed in-place over
// xdt) + chunk prefix + recurrence-free correction pass.
// Shapes: B=4, L=8192, d_model=128, d_inner=256, d_state=16, dt_rank=8.
#define NB   4
#define LSEQ 8192
#define DM   128
#define DI   256
#define NS   16
#define RK   8
#define NCH  256          // chunks over L
#define LC   32           // L / NCH
#define MTOT (NB*LSEQ)
#define LOG2E 1.44269504088896340736f
#define LN2f  0.69314718055994530942f

#if __has_builtin(__builtin_amdgcn_exp2f)
__device__ __forceinline__ float fexp2(float x){ return __builtin_amdgcn_exp2f(x); }
#else
__device__ __forceinline__ float fexp2(float x){ return exp2f(x); }
#endif
#if __has_builtin(__builtin_amdgcn_logf)
__device__ __forceinline__ float flog2(float x){ return __builtin_amdgcn_logf(x); }
#else
__device__ __forceinline__ float flog2(float x){ return log2f(x); }
#endif
#if __has_builtin(__builtin_amdgcn_rcpf)
__device__ __forceinline__ float frcp(float x){ return __builtin_amdgcn_rcpf(x); }
#else
__device__ __forceinline__ float frcp(float x){ return 1.f/x; }
#endif
__device__ __forceinline__ float fexpn(float x){ return fexp2(x*LOG2E); }
__device__ __forceinline__ float fsilu(float x){ return x*frcp(1.f + fexpn(-x)); }
__device__ __forceinline__ float fsoftplus(float x){
  return fmaxf(x,0.f) + flog2(1.f + fexpn(-fabsf(x)))*LN2f;
}

__device__ __forceinline__ unsigned short f2bf(float v){
  unsigned int u = __float_as_uint(v);
  return (unsigned short)((u + 0x7FFFu + ((u >> 16) & 1u)) >> 16);
}
__device__ __forceinline__ float bf2f(unsigned short h){
  return __uint_as_float(((unsigned int)h) << 16);
}

typedef __attribute__((ext_vector_type(8))) short bf16x8;
typedef __attribute__((ext_vector_type(4))) float f32x4;
typedef __attribute__((ext_vector_type(2))) float f32x2;

#if __has_builtin(__builtin_elementwise_fma)
__device__ __forceinline__ f32x2 pkfma(f32x2 a, f32x2 b, f32x2 c){ return __builtin_elementwise_fma(a,b,c); }
#else
__device__ __forceinline__ f32x2 pkfma(f32x2 a, f32x2 b, f32x2 c){ return a*b + c; }
#endif

// ---------------------------------------------------------------------------
// K0: weights -> bf16: in_proj [512][128]; x_proj padded [2][48][256];
// out_proj [128][256].
// ---------------------------------------------------------------------------
__global__ __launch_bounds__(256) void k_prep_w(
    const float* __restrict__ wip, unsigned short* __restrict__ wipbf,
    const float* __restrict__ xwf, const float* __restrict__ xwb, unsigned short* __restrict__ xwbf,
    const float* __restrict__ wop, unsigned short* __restrict__ wopbf)
{
  int i = blockIdx.x*256 + threadIdx.x;      // 0..122879
  if (i < 65536) {
    wipbf[i] = f2bf(wip[i]);
  } else if (i < 90112) {
    int j = i - 65536;                       // 0..24575
    int dirw = j / 12288;
    int rem = j - dirw*12288;
    int row = rem >> 8, k = rem & 255;
    const float* src = dirw ? xwb : xwf;
    xwbf[j] = (row < 40) ? f2bf(src[row*256 + k]) : (unsigned short)0;
  } else {
    int j = i - 90112;                       // 0..32767
    wopbf[j] = f2bf(wop[j]);
  }
}

// ---------------------------------------------------------------------------
// K1a: LN1 -> xn bf16 [MTOT][128]. Reads x [B,128,L] coalesced.
// ---------------------------------------------------------------------------
__global__ __launch_bounds__(256) void k_ln(
    const float* __restrict__ x, const float* __restrict__ ln1w, const float* __restrict__ ln1b,
    unsigned short* __restrict__ xnbf)
{
  __shared__ float a_s[DM][65];
  __shared__ float mS[64], rS[64];
  const int tid = threadIdx.x;
  const int m0 = blockIdx.x * 64;
  const int b = m0 >> 13, l0 = m0 & (LSEQ-1);
  const float* xb = x + b*DM*LSEQ;
#pragma unroll
  for (int i = 0; i < 32; ++i) {
    int idx = tid + i*256;
    int d = idx >> 6, l = idx & 63;
    a_s[d][l] = xb[d*LSEQ + l0 + l];
  }
  __syncthreads();
  {
    int p = tid & 3, l = tid >> 2;
    float s = 0.f, q = 0.f;
#pragma unroll
    for (int jj = 0; jj < 32; ++jj) {
      float v = a_s[p + 4*jj][l];
      s += v; q += v*v;
    }
    s += __shfl_xor(s,1); s += __shfl_xor(s,2);
    q += __shfl_xor(q,1); q += __shfl_xor(q,2);
    float m = s*(1.f/DM);
    float var = q*(1.f/DM) - m*m;
    if (p == 0) { mS[l] = m; rS[l] = rsqrtf(var + 1e-5f); }
  }
  __syncthreads();
#pragma unroll
  for (int i = 0; i < 32; ++i) {
    int idx = tid + i*256;
    int l = idx >> 7, d = idx & 127;
    float v = (a_s[d][l] - mS[l])*rS[l]*ln1w[d] + ln1b[d];
    xnbf[(m0+l)*DM + d] = f2bf(v);
  }
}

// ---------------------------------------------------------------------------
// K1b: in_proj GEMM via bf16 MFMA (single plane). Tile 64x64, K=128.
// n0<256 -> xib (bf16); n0>=256 -> zzb = silu(z) bf16.
// ---------------------------------------------------------------------------
__global__ __launch_bounds__(256) void k_gemm_in(
    const unsigned short* __restrict__ xnbf, const unsigned short* __restrict__ wipbf,
    unsigned short* __restrict__ xib, unsigned short* __restrict__ zzb)
{
  __shared__ char lds[32768];                 // 2 planes x 16KB (64 rows x 128 bf16)
  const int tid = threadIdx.x;
  const int m0 = blockIdx.x * 64;
  const int n0 = blockIdx.y * 64;
  const unsigned short* srcs[2] = { xnbf + m0*DM, wipbf + n0*DM };
#pragma unroll
  for (int p = 0; p < 2; ++p) {
#pragma unroll
    for (int i = 0; i < 4; ++i) {
      int u = tid + i*256;                    // 16B unit within plane
      int row = u >> 4, c = u & 15;
      int dstu = p*1024 + row*16 + (c ^ (row & 7));
      *(uint4*)(lds + dstu*16) = *(const uint4*)(srcs[p] + row*DM + c*8);
    }
  }
  __syncthreads();
  const int wid = tid >> 6, lane = tid & 63;
  const int m0w = (wid & 1)*32, n0w = (wid >> 1)*32;
  const int lr = lane & 15, kg = lane >> 4;
  bf16x8 af[2][4], bfv[2][4];
#pragma unroll
  for (int mi = 0; mi < 2; ++mi) {
    int row = m0w + mi*16 + lr;
#pragma unroll
    for (int kk = 0; kk < 4; ++kk) {
      int slot = (kk*4 + kg) ^ (row & 7);
      af[mi][kk] = *(const bf16x8*)(lds + row*256 + slot*16);
    }
  }
#pragma unroll
  for (int nj = 0; nj < 2; ++nj) {
    int row = n0w + nj*16 + lr;
#pragma unroll
    for (int kk = 0; kk < 4; ++kk) {
      int slot = (kk*4 + kg) ^ (row & 7);
      bfv[nj][kk] = *(const bf16x8*)(lds + 16384 + row*256 + slot*16);
    }
  }
  f32x4 acc[2][2];
#pragma unroll
  for (int mi = 0; mi < 2; ++mi)
#pragma unroll
    for (int nj = 0; nj < 2; ++nj) acc[mi][nj] = 0.f;
#pragma unroll
  for (int kk = 0; kk < 4; ++kk)
#pragma unroll
    for (int mi = 0; mi < 2; ++mi)
#pragma unroll
      for (int nj = 0; nj < 2; ++nj)
        acc[mi][nj] = __builtin_amdgcn_mfma_f32_16x16x32_bf16(af[mi][kk], bfv[nj][kk], acc[mi][nj], 0,0,0);
  // C/D: col = lane&15 (n), row = (lane>>4)*4 + r (m)
  if (n0 < 256) {
#pragma unroll
    for (int mi = 0; mi < 2; ++mi)
#pragma unroll
      for (int nj = 0; nj < 2; ++nj) {
        int n_g = n0 + n0w + nj*16 + lr;
#pragma unroll
        for (int r = 0; r < 4; ++r) {
          int m_g = m0 + m0w + mi*16 + kg*4 + r;
          xib[(size_t)m_g*DI + n_g] = f2bf(acc[mi][nj][r]);
        }
      }
  } else {
#pragma unroll
    for (int mi = 0; mi < 2; ++mi)
#pragma unroll
      for (int nj = 0; nj < 2; ++nj) {
        int n_g = (n0 - 256) + n0w + nj*16 + lr;
#pragma unroll
        for (int r = 0; r < 4; ++r) {
          int m_g = m0 + m0w + mi*16 + kg*4 + r;
          zzb[(size_t)m_g*DI + n_g] = f2bf(fsilu(acc[mi][nj][r]));
        }
      }
  }
}

// ---------------------------------------------------------------------------
// K2: conv4+SiLU -> xc into LDS A-plane; x_proj MFMA (dt_r -> LDS, B/C ->
// interleaved BC[row][32]); dt = softplus, xc|dt packed into uint4 groups:
// xdt4[(db*(L/4) + l/4)*DI + d].
// ---------------------------------------------------------------------------
__global__ __launch_bounds__(256) void k_conv_xproj(
  const unsigned short* __restrict__ xib,
  const float* __restrict__ cwf, const float* __restrict__ cbf,
  const float* __restrict__ cwb, const float* __restrict__ cbb,
  const unsigned short* __restrict__ xwbf,   // [2][48][256] bf16
  const float* __restrict__ dtwf, const float* __restrict__ dtbf,
  const float* __restrict__ dtwb, const float* __restrict__ dtbb,
  float* __restrict__ BC,
  uint4* __restrict__ xdt4)
{
  __shared__ char lds[57344];   // A: 64x512B @0; W: 48x512B @32768
  __shared__ float dtr_s[64][8];
  const int tid = threadIdx.x, bid = blockIdx.x;
  const int lt = bid & (LSEQ/64 - 1);
  const int b  = (bid >> 7) & 3;
  const int dir = bid >> 9;
  const int l0 = lt*64;
  const int db = dir*NB + b;
  const unsigned short* xwp = xwbf + dir*48*256;
#pragma unroll
  for (int i = 0; i < 6; ++i) {
    int u = tid + i*256;
    int row = u >> 5, s = u & 31;
    *(uint4*)(lds + 32768 + row*512 + ((s ^ (row & 7))<<4)) =
        *(const uint4*)(xwp + row*256 + s*8);
  }
  const float* cw  = dir ? cwb : cwf;
  const float* cbp = dir ? cbb : cbf;
  const int d = tid;
  const float w0 = cw[d*4+0], w1 = cw[d*4+1], w2 = cw[d*4+2], w3 = cw[d*4+3];
  const float bias = cbp[d];
  const int g0 = dir ? (LSEQ-1-l0) : l0;
  const int stp = dir ? -DI : DI;
  const unsigned short* xp = xib + (size_t)(b*LSEQ)*DI + d + (size_t)g0*DI;
  float h3 = 0.f, h2 = 0.f, h1 = 0.f;
  if (l0 >= 3) { h3 = bf2f(xp[-3*stp]); h2 = bf2f(xp[-2*stp]); h1 = bf2f(xp[-1*stp]); }
  float r0 = bf2f(xp[0]), r1 = bf2f(xp[stp]), r2 = bf2f(xp[2*stp]), r3 = bf2f(xp[3*stp]);
  for (int j = 0; j < 64; j += 4) {
    float v0 = r0, v1 = r1, v2 = r2, v3 = r3;
    if (j + 4 < 64) {
      const unsigned short* q = xp + (j+4)*stp;
      r0 = bf2f(q[0]); r1 = bf2f(q[stp]); r2 = bf2f(q[2*stp]); r3 = bf2f(q[3*stp]);
    }
#pragma unroll
    for (int u = 0; u < 4; ++u) {
      float vv = (u==0)?v0:(u==1)?v1:(u==2)?v2:v3;
      float a = bias + w0*h3 + w1*h2 + w2*h1 + w3*vv;
      int row = j + u;
      *(unsigned short*)(lds + row*512 + ((((d>>3) ^ (row&7))<<4) + ((d&7)<<1))) = f2bf(fsilu(a));
      h3 = h2; h2 = h1; h1 = vv;
    }
  }
  __syncthreads();
  // ---- phase 2: MFMA [64 rows] x [48 cols], K=256 ----
  const int wid = tid >> 6, lane = tid & 63;
  const int lr = lane & 15, kg = lane >> 4;
  const int arow = wid*16 + lr;
  f32x4 acc[3];
#pragma unroll
  for (int j = 0; j < 3; ++j) acc[j] = 0.f;
#pragma unroll
  for (int t = 0; t < 8; ++t) {
    bf16x8 afv = *(const bf16x8*)(lds + arow*512 + (((t*4+kg) ^ (arow&7))<<4));
#pragma unroll
    for (int j = 0; j < 3; ++j) {
      int wrow = j*16 + lr;
      bf16x8 bfr = *(const bf16x8*)(lds + 32768 + wrow*512 + (((t*4+kg) ^ (wrow&7))<<4));
      acc[j] = __builtin_amdgcn_mfma_f32_16x16x32_bf16(afv, bfr, acc[j], 0,0,0);
    }
  }
  const int base_l = (db*LSEQ + l0) + wid*16 + kg*4;
  const int rloc = wid*16 + kg*4;
#pragma unroll
  for (int j = 0; j < 3; ++j) {
    int col = j*16 + lr;
#pragma unroll
    for (int r = 0; r < 4; ++r) {
      float v = acc[j][r];
      if (col < 8)       dtr_s[rloc + r][col] = v;
      else if (col < 40) BC[(size_t)(base_l + r)*32 + (col - 8)] = v;   // B:0..15, C:16..31
    }
  }
  __syncthreads();
  // ---- phase 3: dt; pack xc|dt; uint4 per 4 rows ----
  const float* dtw = dir ? dtwb : dtwf;
  const float* dtbp= dir ? dtbb : dtbf;
  float dwv[8];
  *(float4*)(dwv+0) = *(const float4*)&dtw[d*RK];
  *(float4*)(dwv+4) = *(const float4*)&dtw[d*RK+4];
  const float dtbv = dtbp[d];
  uint4* xdtp = xdt4 + (size_t)(db*(LSEQ/4) + (l0>>2))*DI + d;
  unsigned int a4[4];
  for (int row = 0; row < 64; ++row) {
    float sd = dtbv;
#pragma unroll
    for (int r = 0; r < RK; ++r) sd = fmaf(dtr_s[row][r], dwv[r], sd);
    unsigned short dtb = f2bf(fsoftplus(sd));
    unsigned short xcb = *(const unsigned short*)(lds + row*512 + ((((d>>3) ^ (row&7))<<4) + ((d&7)<<1)));
    a4[row & 3] = (unsigned int)xcb | ((unsigned int)dtb << 16);
    if ((row & 3) == 3)
      xdtp[(size_t)(row >> 2)*DI] = make_uint4(a4[0], a4[1], a4[2], a4[3]);
  }
}

// ---------------------------------------------------------------------------
// K3: SINGLE scan pass. Per chunk from h=0: per step compute
// y_local = C.h_local + xc*D and cumdt; OVERWRITE xdt group in place with
// packed (y_local bf16 | cumdt bf16). Also emit h_local(end) + sumdt.
// In-place safe: next group's load issues before current group's store,
// per-thread 1:1 indices. (xy deliberately NOT restrict.)
// ---------------------------------------------------------------------------
__global__ __launch_bounds__(256) void k_scan_fwd(
  uint4* xy,
  const float* __restrict__ BC,
  const float* __restrict__ alogf, const float* __restrict__ alogb,
  const float* __restrict__ Dskf, const float* __restrict__ Dskb,
  unsigned short* __restrict__ hloc, float* __restrict__ sumdt)
{
  const int tid = threadIdx.x, bid = blockIdx.x;   // 2048
  const int c = bid & (NCH-1), b = (bid>>8)&3, dir = bid>>10;
  const int db = dir*NB + b;
  const int l0 = c*LC;
  const float* alog = dir ? alogb : alogf;
  const int d = tid;
  const float Dd = (dir ? Dskb : Dskf)[d];
  float A2[NS];
#pragma unroll
  for (int n = 0; n < NS; ++n) A2[n] = -fexpn(alog[d*NS+n]) * LOG2E;
  const float a20 = A2[0];
  bool pw = true;
#pragma unroll
  for (int n = 1; n < NS; ++n) pw = pw && (fabsf(A2[n] - (n+1)*a20) <= 1e-3f*fabsf(A2[n]));
  f32x2 h2[8];
#pragma unroll
  for (int k = 0; k < 8; ++k) h2[k] = 0.f;
  uint4* xq = xy + (size_t)(db*(LSEQ/4) + (l0>>2))*DI + d;
  const float* BCb = BC + (size_t)(db*LSEQ + l0)*32;   // uniform base
  uint4 Xn = xq[0];
  float sac = 0.f;
  for (int g = 0; g < 8; ++g) {
    uint4 cur = Xn;
    if (g + 1 < 8) Xn = xq[(size_t)(g+1)*DI];
    unsigned int us[4] = {cur.x, cur.y, cur.z, cur.w};
    unsigned int outp[4];
#pragma unroll
    for (int u = 0; u < 4; ++u) {
      unsigned int uu = us[u];
      float xc = __uint_as_float(uu << 16);
      float dt = __uint_as_float(uu & 0xffff0000u);
      sac += dt;
      float dx = dt*xc;
      const float4* bq = (const float4*)(BCb + (size_t)(g*4+u)*32);
      float bcl[32];
      *(float4*)(bcl+0)  = bq[0];  *(float4*)(bcl+4)  = bq[1];
      *(float4*)(bcl+8)  = bq[2];  *(float4*)(bcl+12) = bq[3];
      *(float4*)(bcl+16) = bq[4];  *(float4*)(bcl+20) = bq[5];
      *(float4*)(bcl+24) = bq[6];  *(float4*)(bcl+28) = bq[7];
      const f32x2* bb2 = (const f32x2*)bcl;
      const f32x2* cc2 = (const f32x2*)(bcl + 16);
      f32x2 e2[8];
      if (pw) {
        float e1 = fexp2(a20*dt);
        float es = e1*e1;
        f32x2 esq = {es, es};
        e2[0] = (f32x2){e1, es};
#pragma unroll
        for (int k = 1; k < 8; ++k) e2[k] = e2[k-1]*esq;
      } else {
#pragma unroll
        for (int k = 0; k < 8; ++k)
          e2[k] = (f32x2){fexp2(A2[2*k]*dt), fexp2(A2[2*k+1]*dt)};
      }
      f32x2 dx2 = {dx, dx};
      f32x2 yv2 = {0.f, 0.f};
#pragma unroll
      for (int k = 0; k < 8; ++k) {
        h2[k] = pkfma(h2[k], e2[k], bb2[k]*dx2);
        yv2 = pkfma(h2[k], cc2[k], yv2);
      }
      float yv = fmaf(xc, Dd, yv2.x + yv2.y);
      outp[u] = (unsigned int)f2bf(yv) | ((unsigned int)f2bf(sac) << 16);
    }
    xq[(size_t)g*DI] = make_uint4(outp[0], outp[1], outp[2], outp[3]);
  }
  unsigned int hp8[8];
#pragma unroll
  for (int k = 0; k < 8; ++k)
    hp8[k] = (unsigned int)f2bf(h2[k].x) | ((unsigned int)f2bf(h2[k].y) << 16);
  unsigned short* dst = hloc + ((size_t)(db*NCH + c)*DI + d)*NS;
  *(uint4*)(dst)   = *(uint4*)(hp8);
  *(uint4*)(dst+8) = *(uint4*)(hp8+4);
  sumdt[(size_t)(db*NCH + c)*DI + d] = sac;
}

// ---------------------------------------------------------------------------
// K4: sequential prefix over chunks (bf16 h, fp32 carry), 16-deep prefetch,
// IN-PLACE: hloc[c] becomes h_in[c].
// ---------------------------------------------------------------------------
__global__ __launch_bounds__(64) void k_prefix(
  unsigned short* __restrict__ hloc, const float* __restrict__ sumdt,
  const float* __restrict__ alogf, const float* __restrict__ alogb)
{
  const int gid = blockIdx.x*64 + threadIdx.x;   // 32768
  const int n = gid & 15;
  const int d = (gid >> 4) & 255;
  const int db = gid >> 12;
  const float* alog = (db >= NB) ? alogb : alogf;
  const float a2 = -fexpn(alog[d*NS+n]) * LOG2E;
  const int HS = DI*NS;                          // per-chunk stride (ushorts)
  unsigned short* hp = hloc + (size_t)db*NCH*HS + d*NS + n;
  const float* sp = sumdt + (size_t)db*NCH*DI + d;
  float hr = 0.f;
  float bl[16], bs[16];
#pragma unroll
  for (int j = 0; j < 16; ++j) { bl[j] = bf2f(hp[(size_t)j*HS]); bs[j] = sp[(size_t)j*DI]; }
  for (int blk = 0; blk < NCH/16; ++blk) {
    float nl[16], nsv[16];
    if (blk < NCH/16 - 1) {
#pragma unroll
      for (int j = 0; j < 16; ++j) {
        nl[j]  = bf2f(hp[(size_t)(blk*16+16+j)*HS]);
        nsv[j] = sp[(size_t)(blk*16+16+j)*DI];
      }
    }
#pragma unroll
    for (int j = 0; j < 16; ++j) {
      float hl = bl[j];
      hp[(size_t)(blk*16+j)*HS] = f2bf(hr);
      hr = fmaf(fexp2(a2*bs[j]), hr, hl);
    }
    if (blk < NCH/16 - 1) {
#pragma unroll
      for (int j = 0; j < 16; ++j) { bl[j] = nl[j]; bs[j] = nsv[j]; }
    }
  }
}

// ---------------------------------------------------------------------------
// K5: correction pass — NO recurrence. s = (y_local + C.(exp(A*cumdt).h_in))
// * pre-silu'd z. Streams packed (y_local|cumdt) + C rows; fully pipelined.
// ---------------------------------------------------------------------------
__global__ __launch_bounds__(256) void k_correct(
  const uint4* __restrict__ ycd, const unsigned short* __restrict__ zzb,
  const float* __restrict__ BC,
  const unsigned short* __restrict__ hinb,
  const float* __restrict__ alogf, const float* __restrict__ alogb,
  unsigned short* __restrict__ s2bf)
{
  const int tid = threadIdx.x, bid = blockIdx.x;   // 2048
  const int c = bid & (NCH-1), b = (bid>>8)&3, dir = bid>>10;
  const int db = dir*NB + b;
  const int l0 = c*LC;
  const float* alog = dir ? alogb : alogf;
  const int d = tid;
  float A2[NS];
#pragma unroll
  for (int n = 0; n < NS; ++n) A2[n] = -fexpn(alog[d*NS+n]) * LOG2E;
  const float a20 = A2[0];
  bool pw = true;
#pragma unroll
  for (int n = 1; n < NS; ++n) pw = pw && (fabsf(A2[n] - (n+1)*a20) <= 1e-3f*fabsf(A2[n]));
  // h_in (bf16 -> fp32 pairs)
  f32x2 g2[8];
  {
    const unsigned short* hb = hinb + ((size_t)(db*NCH + c)*DI + d)*NS;
    uint4 p0 = *(const uint4*)(hb);
    uint4 p1 = *(const uint4*)(hb+8);
    unsigned int w[8] = {p0.x,p0.y,p0.z,p0.w,p1.x,p1.y,p1.z,p1.w};
#pragma unroll
    for (int k = 0; k < 8; ++k)
      g2[k] = (f32x2){__uint_as_float(w[k] << 16), __uint_as_float(w[k] & 0xffff0000u)};
  }
  const int g0 = dir ? (LSEQ-1-l0) : l0;
  const int stp = dir ? -DI : DI;
  const uint4* yq = ycd + (size_t)(db*(LSEQ/4) + (l0>>2))*DI + d;
  const float* BCb = BC + (size_t)(db*LSEQ + l0)*32;   // uniform base
  const unsigned short* zp = zzb + (size_t)(b*LSEQ + g0)*DI + d;
  unsigned short* sp = s2bf + (size_t)(db*LSEQ + l0)*DI + d;
  uint4 Xn = yq[0];
  for (int g = 0; g < 8; ++g) {
    uint4 cur = Xn;
    if (g + 1 < 8) Xn = yq[(size_t)(g+1)*DI];
    unsigned int us[4] = {cur.x, cur.y, cur.z, cur.w};
#pragma unroll
    for (int u = 0; u < 4; ++u) {
      unsigned int uu = us[u];
      float yl = __uint_as_float(uu << 16);              // y_local
      float cd = __uint_as_float(uu & 0xffff0000u);      // cumdt
      const float4* cq = (const float4*)(BCb + (size_t)(g*4+u)*32 + 16);
      float ccl[16];
      *(float4*)(ccl+0)  = cq[0];  *(float4*)(ccl+4)  = cq[1];
      *(float4*)(ccl+8)  = cq[2];  *(float4*)(ccl+12) = cq[3];
      const f32x2* cc2 = (const f32x2*)ccl;
      f32x2 e2[8];
      if (pw) {
        float e1 = fexp2(a20*cd);
        float es = e1*e1;
        f32x2 esq = {es, es};
        e2[0] = (f32x2){e1, es};
#pragma unroll
        for (int k = 1; k < 8; ++k) e2[k] = e2[k-1]*esq;
      } else {
#pragma unroll
        for (int k = 0; k < 8; ++k)
          e2[k] = (f32x2){fexp2(A2[2*k]*cd), fexp2(A2[2*k+1]*cd)};
      }
      f32x2 yv2 = {0.f, 0.f};
#pragma unroll
      for (int k = 0; k < 8; ++k)
        yv2 = pkfma(g2[k]*e2[k], cc2[k], yv2);
      float s = (yl + yv2.x + yv2.y) * bf2f(zp[(g*4+u)*stp]);  // z pre-silu'd
      sp[(size_t)(g*4+u)*DI] = f2bf(s);
    }
  }
}

// ---------------------------------------------------------------------------
// K6: MFMA out_proj. (sF + rev(sB)) @ W^T == [sF | rev(sB)] @ [W;W]^T.
// Epilogue: +residual, LN2, transposed store.
// ---------------------------------------------------------------------------
__global__ __launch_bounds__(512) void k_out(
  const unsigned short* __restrict__ s2bf,  // [2][NB][LSEQ][DI] bf16
  const unsigned short* __restrict__ wopbf, // [DM][DI] bf16
  const float* __restrict__ x, const float* __restrict__ ln2w, const float* __restrict__ ln2b,
  float* __restrict__ out)
{
  __shared__ char lds[65536];
  const int tid = threadIdx.x;
  const int m0 = blockIdx.x*64;
  const int b = m0 >> 13, l0 = m0 & (LSEQ-1);
  const unsigned short* sF = s2bf + (size_t)b*LSEQ*DI;
  const unsigned short* sB = s2bf + (size_t)(NB + b)*LSEQ*DI;
#pragma unroll
  for (int i = 0; i < 8; ++i) {
    int u = tid + i*512;
    int row = u >> 6, c = u & 63;
    int l = l0 + row;
    const unsigned short* src = (c < 32) ? (sF + (size_t)l*DI + c*8)
                                         : (sB + (size_t)(LSEQ-1-l)*DI + (c-32)*8);
    *(uint4*)(lds + row*1024 + ((c ^ (row & 7))<<4)) = *(const uint4*)src;
  }
  const int wid = tid >> 6;
  const int wr = wid >> 2, wc = wid & 3;
  const int lane = tid & 63, lr = lane & 15, kg = lane >> 4;
  bf16x8 wf[2][8];
#pragma unroll
  for (int nt = 0; nt < 2; ++nt) {
    int n = wc*32 + nt*16 + lr;
#pragma unroll
    for (int kt = 0; kt < 8; ++kt)
      wf[nt][kt] = *(const bf16x8*)(wopbf + n*DI + kt*32 + kg*8);
  }
  __syncthreads();
  f32x4 acc[2][2];
#pragma unroll
  for (int mt = 0; mt < 2; ++mt)
#pragma unroll
    for (int nt = 0; nt < 2; ++nt) acc[mt][nt] = 0.f;
#pragma unroll
  for (int kt2 = 0; kt2 < 16; ++kt2) {
#pragma unroll
    for (int mt = 0; mt < 2; ++mt) {
      int row = wr*32 + mt*16 + lr;
      int slot = (kt2*4 + kg) ^ (row & 7);
      bf16x8 af = *(const bf16x8*)(lds + row*1024 + (slot<<4));
#pragma unroll
      for (int nt = 0; nt < 2; ++nt)
        acc[mt][nt] = __builtin_amdgcn_mfma_f32_16x16x32_bf16(af, wf[nt][kt2 & 7], acc[mt][nt], 0,0,0);
    }
  }
  __syncthreads();
  float* smem = (float*)lds;
  const int RP = 133;
  float* mS = smem + 64*RP;
  float* rS = mS + 64;
  const float* xb = x + b*DM*LSEQ + l0;
#pragma unroll
  for (int mt = 0; mt < 2; ++mt) {
    int mbase = wr*32 + mt*16 + kg*4;
#pragma unroll
    for (int nt = 0; nt < 2; ++nt) {
      int n = wc*32 + nt*16 + lr;
      float4 rx = *(const float4*)&xb[n*LSEQ + mbase];
      smem[(mbase+0)*RP + n] = acc[mt][nt][0] + rx.x;
      smem[(mbase+1)*RP + n] = acc[mt][nt][1] + rx.y;
      smem[(mbase+2)*RP + n] = acc[mt][nt][2] + rx.z;
      smem[(mbase+3)*RP + n] = acc[mt][nt][3] + rx.w;
    }
  }
  __syncthreads();
  {
    int row = tid >> 3, p = tid & 7;
    float s = 0.f, q = 0.f;
#pragma unroll
    for (int jj = 0; jj < 16; ++jj) {
      float v = smem[row*RP + p*16 + jj];
      s += v; q += v*v;
    }
    s += __shfl_xor(s,1); s += __shfl_xor(s,2); s += __shfl_xor(s,4);
    q += __shfl_xor(q,1); q += __shfl_xor(q,2); q += __shfl_xor(q,4);
    if (p == 0) {
      float m = s*(1.f/DM);
      float var = q*(1.f/DM) - m*m;
      mS[row] = m; rS[row] = rsqrtf(var + 1e-5f);
    }
  }
  __syncthreads();
  float* ob = out + b*DM*LSEQ + l0;
#pragma unroll
  for (int i = 0; i < 16; ++i) {
    int idx = tid + i*512;
    int col = idx >> 6, l = idx & 63;
    float v = (smem[l*RP + col] - mS[l])*rS[l]*ln2w[col] + ln2b[col];
    ob[col*LSEQ + l] = v;
  }
}

// ---------------------------------------------------------------------------
extern "C" void kernel_launch(void* const* d_in, const int* in_sizes, int n_in,
                              void* d_out, int out_size, void* d_ws, size_t ws_size,
                              hipStream_t stream)
{
  (void)in_sizes; (void)n_in; (void)out_size; (void)ws_size;
  const float* x     = (const float*)d_in[0];
  const float* ln1w  = (const float*)d_in[1];
  const float* ln1b  = (const float*)d_in[2];
  const float* ln2w  = (const float*)d_in[3];
  const float* ln2b  = (const float*)d_in[4];
  const float* wip   = (const float*)d_in[5];
  const float* wop   = (const float*)d_in[6];
  const float* cwf   = (const float*)d_in[7];
  const float* cbf   = (const float*)d_in[8];
  const float* xwf   = (const float*)d_in[9];
  const float* dtwf  = (const float*)d_in[10];
  const float* dtbf  = (const float*)d_in[11];
  const float* alogf = (const float*)d_in[12];
  const float* Dskf  = (const float*)d_in[13];
  const float* cwb   = (const float*)d_in[14];
  const float* cbb   = (const float*)d_in[15];
  const float* xwb   = (const float*)d_in[16];
  const float* dtwb  = (const float*)d_in[17];
  const float* dtbb  = (const float*)d_in[18];
  const float* alogb = (const float*)d_in[19];
  const float* Dskb  = (const float*)d_in[20];

  // workspace layout (float units)
  float* ws    = (float*)d_ws;
  float* xibF  = ws;                    //  4,194,304 (xib: 8.4M ushort)
  float* zzbF  = xibF  + 4194304;       //  4,194,304 (zzb: 8.4M ushort)
  float* BC    = zzbF  + 4194304;       //  2,097,152 + pad (interleaved B|C)
  float* s2F   = BC    + 2097184;       //  8,388,608 (s2bf: 16.8M ushort)
  float* xdtF  = s2F   + 8388608;       // 16,777,216 (uint4 groups; becomes ycd)
  float* hlocF = xdtF  + 16777216;      //  4,194,304 (bf16: 8.4M ushort)
  float* sumdt = hlocF + 4194304;       //    524,288
  float* xwbfF = sumdt + 524288;        //     12,288 (24,576 bf16)
  float* wopbfF= xwbfF + 12288;         //     16,384 (32,768 bf16)
  float* out   = (float*)d_out;
  // aliases in s2F region (fully rewritten each call):
  unsigned short* xnbf  = (unsigned short*)s2F;             // 4,194,304 ush
  unsigned short* wipbf = (unsigned short*)(s2F + 2097152); //    65,536 ush
  unsigned short* s2bf  = (unsigned short*)s2F;
  unsigned short* xib   = (unsigned short*)xibF;
  unsigned short* zzb   = (unsigned short*)zzbF;
  uint4*          xdt4  = (uint4*)xdtF;
  unsigned short* hloc  = (unsigned short*)hlocF;
  unsigned short* xwbf  = (unsigned short*)xwbfF;
  unsigned short* wopbf = (unsigned short*)wopbfF;

  k_prep_w<<<480, 256, 0, stream>>>(wip, wipbf, xwf, xwb, xwbf, wop, wopbf);
  k_ln<<<512, 256, 0, stream>>>(x, ln1w, ln1b, xnbf);
  k_gemm_in<<<dim3(512,8), 256, 0, stream>>>(xnbf, wipbf, xib, zzb);
  k_conv_xproj<<<1024, 256, 0, stream>>>(xib, cwf,cbf,cwb,cbb, xwbf,
                                         dtwf,dtbf,dtwb,dtbb, BC, xdt4);
  k_scan_fwd<<<2048, 256, 0, stream>>>(xdt4, BC, alogf, alogb, Dskf, Dskb,
                                       hloc, sumdt);
  k_prefix<<<512, 64, 0, stream>>>(hloc, sumdt, alogf, alogb);
  k_correct<<<2048, 256, 0, stream>>>(xdt4, zzb, BC, hloc,
                                      alogf, alogb, s2bf);
  k_out<<<512, 512, 0, stream>>>(s2bf, wopbf, x, ln2w, ln2b, out);
}

// Round 14
// 162.697 us; speedup vs baseline: 1.2758x; 1.1154x over previous
//
#include <hip/hip_runtime.h>

// MambaLayer bidirectional selective-scan (round-9 best config + single-pass
// in_proj GEMM). bf16 MFMA GEMMs, packed xc/dt scan, packed-fp32 state math.
// Shapes: B=4, L=8192, d_model=128, d_inner=256, d_state=16, dt_rank=8.
#define NB   4
#define LSEQ 8192
#define DM   128
#define DI   256
#define NS   16
#define RK   8
#define NCH  256          // chunks over L
#define LC   32           // L / NCH
#define MTOT (NB*LSEQ)
#define LOG2E 1.44269504088896340736f
#define LN2f  0.69314718055994530942f

#if __has_builtin(__builtin_amdgcn_exp2f)
__device__ __forceinline__ float fexp2(float x){ return __builtin_amdgcn_exp2f(x); }
#else
__device__ __forceinline__ float fexp2(float x){ return exp2f(x); }
#endif
#if __has_builtin(__builtin_amdgcn_logf)
__device__ __forceinline__ float flog2(float x){ return __builtin_amdgcn_logf(x); }
#else
__device__ __forceinline__ float flog2(float x){ return log2f(x); }
#endif
#if __has_builtin(__builtin_amdgcn_rcpf)
__device__ __forceinline__ float frcp(float x){ return __builtin_amdgcn_rcpf(x); }
#else
__device__ __forceinline__ float frcp(float x){ return 1.f/x; }
#endif
__device__ __forceinline__ float fexpn(float x){ return fexp2(x*LOG2E); }
__device__ __forceinline__ float fsilu(float x){ return x*frcp(1.f + fexpn(-x)); }
__device__ __forceinline__ float fsoftplus(float x){
  return fmaxf(x,0.f) + flog2(1.f + fexpn(-fabsf(x)))*LN2f;
}

__device__ __forceinline__ unsigned short f2bf(float v){
  unsigned int u = __float_as_uint(v);
  return (unsigned short)((u + 0x7FFFu + ((u >> 16) & 1u)) >> 16);
}
__device__ __forceinline__ float bf2f(unsigned short h){
  return __uint_as_float(((unsigned int)h) << 16);
}

typedef __attribute__((ext_vector_type(8))) short bf16x8;
typedef __attribute__((ext_vector_type(4))) float f32x4;
typedef __attribute__((ext_vector_type(2))) float f32x2;

#if __has_builtin(__builtin_elementwise_fma)
__device__ __forceinline__ f32x2 pkfma(f32x2 a, f32x2 b, f32x2 c){ return __builtin_elementwise_fma(a,b,c); }
#else
__device__ __forceinline__ f32x2 pkfma(f32x2 a, f32x2 b, f32x2 c){ return a*b + c; }
#endif

// ---------------------------------------------------------------------------
// K0: weights -> bf16: in_proj [512][128]; x_proj padded [2][48][256];
// out_proj [128][256].
// ---------------------------------------------------------------------------
__global__ __launch_bounds__(256) void k_prep_w(
    const float* __restrict__ wip, unsigned short* __restrict__ wipbf,
    const float* __restrict__ xwf, const float* __restrict__ xwb, unsigned short* __restrict__ xwbf,
    const float* __restrict__ wop, unsigned short* __restrict__ wopbf)
{
  int i = blockIdx.x*256 + threadIdx.x;      // 0..122879
  if (i < 65536) {
    wipbf[i] = f2bf(wip[i]);
  } else if (i < 90112) {
    int j = i - 65536;                       // 0..24575
    int dirw = j / 12288;
    int rem = j - dirw*12288;
    int row = rem >> 8, k = rem & 255;
    const float* src = dirw ? xwb : xwf;
    xwbf[j] = (row < 40) ? f2bf(src[row*256 + k]) : (unsigned short)0;
  } else {
    int j = i - 90112;                       // 0..32767
    wopbf[j] = f2bf(wop[j]);
  }
}

// ---------------------------------------------------------------------------
// K1a: LN1 -> xn bf16 [MTOT][128]. Reads x [B,128,L] coalesced.
// ---------------------------------------------------------------------------
__global__ __launch_bounds__(256) void k_ln(
    const float* __restrict__ x, const float* __restrict__ ln1w, const float* __restrict__ ln1b,
    unsigned short* __restrict__ xnbf)
{
  __shared__ float a_s[DM][65];
  __shared__ float mS[64], rS[64];
  const int tid = threadIdx.x;
  const int m0 = blockIdx.x * 64;
  const int b = m0 >> 13, l0 = m0 & (LSEQ-1);
  const float* xb = x + b*DM*LSEQ;
#pragma unroll
  for (int i = 0; i < 32; ++i) {
    int idx = tid + i*256;
    int d = idx >> 6, l = idx & 63;
    a_s[d][l] = xb[d*LSEQ + l0 + l];
  }
  __syncthreads();
  {
    int p = tid & 3, l = tid >> 2;
    float s = 0.f, q = 0.f;
#pragma unroll
    for (int jj = 0; jj < 32; ++jj) {
      float v = a_s[p + 4*jj][l];
      s += v; q += v*v;
    }
    s += __shfl_xor(s,1); s += __shfl_xor(s,2);
    q += __shfl_xor(q,1); q += __shfl_xor(q,2);
    float m = s*(1.f/DM);
    float var = q*(1.f/DM) - m*m;
    if (p == 0) { mS[l] = m; rS[l] = rsqrtf(var + 1e-5f); }
  }
  __syncthreads();
#pragma unroll
  for (int i = 0; i < 32; ++i) {
    int idx = tid + i*256;
    int l = idx >> 7, d = idx & 127;
    float v = (a_s[d][l] - mS[l])*rS[l]*ln1w[d] + ln1b[d];
    xnbf[(m0+l)*DM + d] = f2bf(v);
  }
}

// ---------------------------------------------------------------------------
// K1b: in_proj GEMM via bf16 MFMA, SINGLE-PASS: grid 512 row-tiles; A-tile
// staged to LDS once, A-frags kept in registers, loop over 8 n-tiles with W
// fragments loaded directly from global (L2-hot, 128KB total).
// n-tiles 0..3 -> xib (bf16); 4..7 -> zzb = silu(z) bf16.
// ---------------------------------------------------------------------------
__global__ __launch_bounds__(256) void k_gemm_in(
    const unsigned short* __restrict__ xnbf, const unsigned short* __restrict__ wipbf,
    unsigned short* __restrict__ xib, unsigned short* __restrict__ zzb)
{
  __shared__ char lds[16384];                 // A plane: 64 rows x 128 bf16, swizzled
  const int tid = threadIdx.x;
  const int m0 = blockIdx.x * 64;
  const unsigned short* asrc = xnbf + (size_t)m0*DM;
#pragma unroll
  for (int i = 0; i < 4; ++i) {
    int u = tid + i*256;                      // 16B unit (0..1023)
    int row = u >> 4, c = u & 15;
    int dstu = row*16 + (c ^ (row & 7));
    *(uint4*)(lds + dstu*16) = *(const uint4*)(asrc + row*DM + c*8);
  }
  __syncthreads();
  const int wid = tid >> 6, lane = tid & 63;
  const int m0w = (wid & 1)*32, nql = (wid >> 1)*32;   // m / n split within tile
  const int lr = lane & 15, kg = lane >> 4;
  bf16x8 af[2][4];
#pragma unroll
  for (int mi = 0; mi < 2; ++mi) {
    int row = m0w + mi*16 + lr;
#pragma unroll
    for (int kk = 0; kk < 4; ++kk) {
      int slot = (kk*4 + kg) ^ (row & 7);
      af[mi][kk] = *(const bf16x8*)(lds + row*256 + slot*16);
    }
  }
  for (int t = 0; t < 8; ++t) {
    const int n0 = t*64;
    bf16x8 bfv[2][4];
#pragma unroll
    for (int nj = 0; nj < 2; ++nj) {
      int nrow = n0 + nql + nj*16 + lr;
#pragma unroll
      for (int kk = 0; kk < 4; ++kk)
        bfv[nj][kk] = *(const bf16x8*)(wipbf + nrow*DM + kk*32 + kg*8);
    }
    f32x4 acc[2][2];
#pragma unroll
    for (int mi = 0; mi < 2; ++mi)
#pragma unroll
      for (int nj = 0; nj < 2; ++nj) acc[mi][nj] = 0.f;
#pragma unroll
    for (int kk = 0; kk < 4; ++kk)
#pragma unroll
      for (int mi = 0; mi < 2; ++mi)
#pragma unroll
        for (int nj = 0; nj < 2; ++nj)
          acc[mi][nj] = __builtin_amdgcn_mfma_f32_16x16x32_bf16(af[mi][kk], bfv[nj][kk], acc[mi][nj], 0,0,0);
    // C/D: col = lane&15 (n), row = (lane>>4)*4 + r (m)
    if (t < 4) {
#pragma unroll
      for (int mi = 0; mi < 2; ++mi)
#pragma unroll
        for (int nj = 0; nj < 2; ++nj) {
          int n_g = n0 + nql + nj*16 + lr;
#pragma unroll
          for (int r = 0; r < 4; ++r) {
            int m_g = m0 + m0w + mi*16 + kg*4 + r;
            xib[(size_t)m_g*DI + n_g] = f2bf(acc[mi][nj][r]);
          }
        }
    } else {
#pragma unroll
      for (int mi = 0; mi < 2; ++mi)
#pragma unroll
        for (int nj = 0; nj < 2; ++nj) {
          int n_g = (n0 - 256) + nql + nj*16 + lr;
#pragma unroll
          for (int r = 0; r < 4; ++r) {
            int m_g = m0 + m0w + mi*16 + kg*4 + r;
            zzb[(size_t)m_g*DI + n_g] = f2bf(fsilu(acc[mi][nj][r]));
          }
        }
    }
  }
}

// ---------------------------------------------------------------------------
// K2: conv4+SiLU -> xc into LDS A-plane (phase1); x_proj MFMA (phase2,
// dt_r -> LDS, B/C -> global); phase3: dt = softplus(dt_r@dtw+b), read xc
// back from LDS, ONE packed 4B store per (l,d): lo = xc bf16, hi = dt bf16.
// ---------------------------------------------------------------------------
__global__ __launch_bounds__(256) void k_conv_xproj(
  const unsigned short* __restrict__ xib,
  const float* __restrict__ cwf, const float* __restrict__ cbf,
  const float* __restrict__ cwb, const float* __restrict__ cbb,
  const unsigned short* __restrict__ xwbf,   // [2][48][256] bf16
  const float* __restrict__ dtwf, const float* __restrict__ dtbf,
  const float* __restrict__ dtwb, const float* __restrict__ dtbb,
  float* __restrict__ Bm, float* __restrict__ Cm,
  unsigned int* __restrict__ xdt)
{
  __shared__ char lds[57344];   // A: 64x512B @0; W: 48x512B @32768
  __shared__ float dtr_s[64][8];
  const int tid = threadIdx.x, bid = blockIdx.x;
  const int lt = bid & (LSEQ/64 - 1);
  const int b  = (bid >> 7) & 3;
  const int dir = bid >> 9;
  const int l0 = lt*64;
  const int db = dir*NB + b;
  const unsigned short* xwp = xwbf + dir*48*256;
#pragma unroll
  for (int i = 0; i < 6; ++i) {
    int u = tid + i*256;
    int row = u >> 5, s = u & 31;
    *(uint4*)(lds + 32768 + row*512 + ((s ^ (row & 7))<<4)) =
        *(const uint4*)(xwp + row*256 + s*8);
  }
  const float* cw  = dir ? cwb : cwf;
  const float* cbp = dir ? cbb : cbf;
  const int d = tid;
  const float w0 = cw[d*4+0], w1 = cw[d*4+1], w2 = cw[d*4+2], w3 = cw[d*4+3];
  const float bias = cbp[d];
  const int g0 = dir ? (LSEQ-1-l0) : l0;
  const int stp = dir ? -DI : DI;
  const unsigned short* xp = xib + (size_t)(b*LSEQ)*DI + d + (size_t)g0*DI;
  float h3 = 0.f, h2 = 0.f, h1 = 0.f;
  if (l0 >= 3) { h3 = bf2f(xp[-3*stp]); h2 = bf2f(xp[-2*stp]); h1 = bf2f(xp[-1*stp]); }
  float r0 = bf2f(xp[0]), r1 = bf2f(xp[stp]), r2 = bf2f(xp[2*stp]), r3 = bf2f(xp[3*stp]);
  for (int j = 0; j < 64; j += 4) {
    float v0 = r0, v1 = r1, v2 = r2, v3 = r3;
    if (j + 4 < 64) {
      const unsigned short* q = xp + (j+4)*stp;
      r0 = bf2f(q[0]); r1 = bf2f(q[stp]); r2 = bf2f(q[2*stp]); r3 = bf2f(q[3*stp]);
    }
#pragma unroll
    for (int u = 0; u < 4; ++u) {
      float vv = (u==0)?v0:(u==1)?v1:(u==2)?v2:v3;
      float a = bias + w0*h3 + w1*h2 + w2*h1 + w3*vv;
      int row = j + u;
      *(unsigned short*)(lds + row*512 + ((((d>>3) ^ (row&7))<<4) + ((d&7)<<1))) = f2bf(fsilu(a));
      h3 = h2; h2 = h1; h1 = vv;
    }
  }
  __syncthreads();
  // ---- phase 2: MFMA [64 rows] x [48 cols], K=256 ----
  const int wid = tid >> 6, lane = tid & 63;
  const int lr = lane & 15, kg = lane >> 4;
  const int arow = wid*16 + lr;
  f32x4 acc[3];
#pragma unroll
  for (int j = 0; j < 3; ++j) acc[j] = 0.f;
#pragma unroll
  for (int t = 0; t < 8; ++t) {
    bf16x8 afv = *(const bf16x8*)(lds + arow*512 + (((t*4+kg) ^ (arow&7))<<4));
#pragma unroll
    for (int j = 0; j < 3; ++j) {
      int wrow = j*16 + lr;
      bf16x8 bfr = *(const bf16x8*)(lds + 32768 + wrow*512 + (((t*4+kg) ^ (wrow&7))<<4));
      acc[j] = __builtin_amdgcn_mfma_f32_16x16x32_bf16(afv, bfr, acc[j], 0,0,0);
    }
  }
  const int base_l = (db*LSEQ + l0) + wid*16 + kg*4;
  const int rloc = wid*16 + kg*4;
#pragma unroll
  for (int j = 0; j < 3; ++j) {
    int col = j*16 + lr;
#pragma unroll
    for (int r = 0; r < 4; ++r) {
      float v = acc[j][r];
      if (col < 8)       dtr_s[rloc + r][col] = v;
      else if (col < 24) Bm[(size_t)(base_l + r)*NS + col - 8] = v;
      else if (col < 40) Cm[(size_t)(base_l + r)*NS + col - 24] = v;
    }
  }
  __syncthreads();
  // ---- phase 3: dt = softplus(dtr @ dtw[d] + b[d]); pack with xc (from LDS)
  const float* dtw = dir ? dtwb : dtwf;
  const float* dtbp= dir ? dtbb : dtbf;
  float dwv[8];
  *(float4*)(dwv+0) = *(const float4*)&dtw[d*RK];
  *(float4*)(dwv+4) = *(const float4*)&dtw[d*RK+4];
  const float dtbv = dtbp[d];
  unsigned int* xdtp = xdt + (size_t)(db*LSEQ + l0)*DI + d;
  for (int row = 0; row < 64; ++row) {
    float sd = dtbv;
#pragma unroll
    for (int r = 0; r < RK; ++r) sd = fmaf(dtr_s[row][r], dwv[r], sd);
    unsigned short dtb = f2bf(fsoftplus(sd));
    unsigned short xcb = *(const unsigned short*)(lds + row*512 + ((((d>>3) ^ (row&7))<<4) + ((d&7)<<1)));
    xdtp[(size_t)row*DI] = (unsigned int)xcb | ((unsigned int)dtb << 16);
  }
}

// ---------------------------------------------------------------------------
// K3: chunk-local scan from h=0 -> h_local (bf16) + sum(dt).
// Packed-fp32 state math (f32x2 -> v_pk_fma_f32), LDS B staging.
// ---------------------------------------------------------------------------
__global__ __launch_bounds__(256) void k_scan_local(
  const unsigned int* __restrict__ xdt, const float* __restrict__ Bm,
  const float* __restrict__ alogf, const float* __restrict__ alogb,
  unsigned short* __restrict__ hloc, float* __restrict__ sumdt)
{
  __shared__ float Bc[LC][NS];
  const int tid = threadIdx.x, bid = blockIdx.x;
  const int c = bid & (NCH-1), b = (bid>>8)&3, dir = bid>>10;
  const int db = dir*NB + b;
  const int l0 = c*LC;
  for (int i = tid; i < LC*NS; i += 256) (&Bc[0][0])[i] = Bm[(size_t)(db*LSEQ + l0)*NS + i];
  const float* alog = dir ? alogb : alogf;
  const int d = tid;
  float A2[NS];
#pragma unroll
  for (int n = 0; n < NS; ++n) A2[n] = -fexpn(alog[d*NS+n]) * LOG2E;
  const float a20 = A2[0];
  bool pw = true;
#pragma unroll
  for (int n = 1; n < NS; ++n) pw = pw && (fabsf(A2[n] - (n+1)*a20) <= 1e-3f*fabsf(A2[n]));
  f32x2 h2[8];
#pragma unroll
  for (int k = 0; k < 8; ++k) h2[k] = 0.f;
  const unsigned int* xp = xdt + (size_t)(db*LSEQ + l0)*DI + d;
  unsigned int u0 = xp[0], u1 = xp[DI], u2 = xp[2*DI], u3 = xp[3*DI];
  __syncthreads();
  float sac = 0.f;
  for (int j = 0; j < LC; j += 4) {
    unsigned int w0=u0, w1=u1, w2=u2, w3=u3;
    if (j + 4 < LC) {
      const unsigned int* q = xp + (size_t)(j+4)*DI;
      u0=q[0]; u1=q[DI]; u2=q[2*DI]; u3=q[3*DI];
    }
#pragma unroll
    for (int u = 0; u < 4; ++u) {
      unsigned int uu = (u==0)?w0:(u==1)?w1:(u==2)?w2:w3;
      float xc = __uint_as_float(uu << 16);
      float dt = __uint_as_float(uu & 0xffff0000u);
      sac += dt;
      float dx = dt*xc;
      f32x2 e2[8];
      if (pw) {
        float e1 = fexp2(a20*dt);
        float es = e1*e1;
        f32x2 esq = {es, es};
        e2[0] = (f32x2){e1, es};
#pragma unroll
        for (int k = 1; k < 8; ++k) e2[k] = e2[k-1]*esq;
      } else {
#pragma unroll
        for (int k = 0; k < 8; ++k)
          e2[k] = (f32x2){fexp2(A2[2*k]*dt), fexp2(A2[2*k+1]*dt)};
      }
      const f32x2* bb2 = (const f32x2*)&Bc[j+u][0];
      f32x2 dx2 = {dx, dx};
#pragma unroll
      for (int k = 0; k < 8; ++k) h2[k] = pkfma(h2[k], e2[k], bb2[k]*dx2);
    }
  }
  // pack h -> bf16, 32B store
  unsigned int hp8[8];
#pragma unroll
  for (int k = 0; k < 8; ++k)
    hp8[k] = (unsigned int)f2bf(h2[k].x) | ((unsigned int)f2bf(h2[k].y) << 16);
  unsigned short* dst = hloc + ((size_t)(db*NCH + c)*DI + d)*NS;
  *(uint4*)(dst)   = *(uint4*)(hp8);
  *(uint4*)(dst+8) = *(uint4*)(hp8+4);
  sumdt[(size_t)(db*NCH + c)*DI + d] = sac;
}

// ---------------------------------------------------------------------------
// K4: sequential prefix over chunks (bf16 h, fp32 carry), 16-deep prefetch,
// IN-PLACE: hloc[c] becomes h_in[c].
// ---------------------------------------------------------------------------
__global__ __launch_bounds__(64) void k_prefix(
  unsigned short* __restrict__ hloc, const float* __restrict__ sumdt,
  const float* __restrict__ alogf, const float* __restrict__ alogb)
{
  const int gid = blockIdx.x*64 + threadIdx.x;   // 32768
  const int n = gid & 15;
  const int d = (gid >> 4) & 255;
  const int db = gid >> 12;
  const float* alog = (db >= NB) ? alogb : alogf;
  const float a2 = -fexpn(alog[d*NS+n]) * LOG2E;
  const int HS = DI*NS;                          // per-chunk stride (ushorts)
  unsigned short* hp = hloc + (size_t)db*NCH*HS + d*NS + n;
  const float* sp = sumdt + (size_t)db*NCH*DI + d;
  float hr = 0.f;
  float bl[16], bs[16];
#pragma unroll
  for (int j = 0; j < 16; ++j) { bl[j] = bf2f(hp[(size_t)j*HS]); bs[j] = sp[(size_t)j*DI]; }
  for (int blk = 0; blk < NCH/16; ++blk) {
    float nl[16], nsv[16];
    if (blk < NCH/16 - 1) {
#pragma unroll
      for (int j = 0; j < 16; ++j) {
        nl[j]  = bf2f(hp[(size_t)(blk*16+16+j)*HS]);
        nsv[j] = sp[(size_t)(blk*16+16+j)*DI];
      }
    }
#pragma unroll
    for (int j = 0; j < 16; ++j) {
      float hl = bl[j];
      hp[(size_t)(blk*16+j)*HS] = f2bf(hr);
      hr = fmaf(fexp2(a2*bs[j]), hr, hl);
    }
    if (blk < NCH/16 - 1) {
#pragma unroll
      for (int j = 0; j < 16; ++j) { bl[j] = nl[j]; bs[j] = nsv[j]; }
    }
  }
}

// ---------------------------------------------------------------------------
// K5: rescan from h_in producing y, + D-skip, * pre-silu'd z -> s (bf16).
// Packed-fp32 state math, LDS B/C staging.
// ---------------------------------------------------------------------------
__global__ __launch_bounds__(256) void k_scan_out(
  const unsigned int* __restrict__ xdt, const unsigned short* __restrict__ zzb,
  const float* __restrict__ Bm, const float* __restrict__ Cm,
  const unsigned short* __restrict__ hinb,
  const float* __restrict__ alogf, const float* __restrict__ alogb,
  const float* __restrict__ Dskf, const float* __restrict__ Dskb,
  unsigned short* __restrict__ s2bf)
{
  __shared__ float Bc[LC][NS];
  __shared__ float Cc[LC][NS];
  const int tid = threadIdx.x, bid = blockIdx.x;
  const int c = bid & (NCH-1), b = (bid>>8)&3, dir = bid>>10;
  const int db = dir*NB + b;
  const int l0 = c*LC;
  for (int i = tid; i < LC*NS; i += 256) (&Bc[0][0])[i] = Bm[(size_t)(db*LSEQ + l0)*NS + i];
  for (int i = tid; i < LC*NS; i += 256) (&Cc[0][0])[i] = Cm[(size_t)(db*LSEQ + l0)*NS + i];
  const float* alog = dir ? alogb : alogf;
  const int d = tid;
  const float Dd = (dir ? Dskb : Dskf)[d];
  float A2[NS];
#pragma unroll
  for (int n = 0; n < NS; ++n) A2[n] = -fexpn(alog[d*NS+n]) * LOG2E;
  const float a20 = A2[0];
  bool pw = true;
#pragma unroll
  for (int n = 1; n < NS; ++n) pw = pw && (fabsf(A2[n] - (n+1)*a20) <= 1e-3f*fabsf(A2[n]));
  // h_in (bf16 -> fp32)
  f32x2 h2[8];
  {
    const unsigned short* hb = hinb + ((size_t)(db*NCH + c)*DI + d)*NS;
    uint4 p0 = *(const uint4*)(hb);
    uint4 p1 = *(const uint4*)(hb+8);
    unsigned int w[8] = {p0.x,p0.y,p0.z,p0.w,p1.x,p1.y,p1.z,p1.w};
#pragma unroll
    for (int k = 0; k < 8; ++k)
      h2[k] = (f32x2){__uint_as_float(w[k] << 16), __uint_as_float(w[k] & 0xffff0000u)};
  }
  const int g0 = dir ? (LSEQ-1-l0) : l0;
  const int stp = dir ? -DI : DI;
  const unsigned int* xp = xdt + (size_t)(db*LSEQ + l0)*DI + d;
  const unsigned short* zp = zzb + (size_t)(b*LSEQ + g0)*DI + d;
  unsigned short* sp = s2bf + (size_t)(db*LSEQ + l0)*DI + d;
  unsigned int u0 = xp[0], u1 = xp[DI], u2 = xp[2*DI], u3 = xp[3*DI];
  unsigned short z0 = zp[0], z1 = zp[stp], z2 = zp[2*stp], z3 = zp[3*stp];
  __syncthreads();
  for (int j = 0; j < LC; j += 4) {
    unsigned int w0=u0, w1=u1, w2=u2, w3=u3;
    unsigned short y0=z0, y1=z1, y2=z2, y3=z3;
    if (j + 4 < LC) {
      const unsigned int* q = xp + (size_t)(j+4)*DI;
      u0=q[0]; u1=q[DI]; u2=q[2*DI]; u3=q[3*DI];
      const unsigned short* qz = zp + (j+4)*stp;
      z0=qz[0]; z1=qz[stp]; z2=qz[2*stp]; z3=qz[3*stp];
    }
#pragma unroll
    for (int u = 0; u < 4; ++u) {
      unsigned int uu = (u==0)?w0:(u==1)?w1:(u==2)?w2:w3;
      unsigned short zu = (u==0)?y0:(u==1)?y1:(u==2)?y2:y3;
      float xc = __uint_as_float(uu << 16);
      float dt = __uint_as_float(uu & 0xffff0000u);
      float dx = dt*xc;
      f32x2 e2[8];
      if (pw) {
        float e1 = fexp2(a20*dt);
        float es = e1*e1;
        f32x2 esq = {es, es};
        e2[0] = (f32x2){e1, es};
#pragma unroll
        for (int k = 1; k < 8; ++k) e2[k] = e2[k-1]*esq;
      } else {
#pragma unroll
        for (int k = 0; k < 8; ++k)
          e2[k] = (f32x2){fexp2(A2[2*k]*dt), fexp2(A2[2*k+1]*dt)};
      }
      const f32x2* bb2 = (const f32x2*)&Bc[j+u][0];
      const f32x2* cc2 = (const f32x2*)&Cc[j+u][0];
      f32x2 dx2 = {dx, dx};
      f32x2 yv2 = {0.f, 0.f};
#pragma unroll
      for (int k = 0; k < 8; ++k) {
        h2[k] = pkfma(h2[k], e2[k], bb2[k]*dx2);
        yv2 = pkfma(h2[k], cc2[k], yv2);
      }
      float yv = yv2.x + yv2.y;
      yv = fmaf(xc, Dd, yv);
      sp[(size_t)(j+u)*DI] = f2bf(yv * bf2f(zu));   // z pre-silu'd in k_gemm_in
    }
  }
}

// ---------------------------------------------------------------------------
// K6: MFMA out_proj. (sF + rev(sB)) @ W^T == [sF | rev(sB)] @ [W;W]^T.
// Epilogue: +residual, LN2, transposed store.
// ---------------------------------------------------------------------------
__global__ __launch_bounds__(512) void k_out(
  const unsigned short* __restrict__ s2bf,  // [2][NB][LSEQ][DI] bf16
  const unsigned short* __restrict__ wopbf, // [DM][DI] bf16
  const float* __restrict__ x, const float* __restrict__ ln2w, const float* __restrict__ ln2b,
  float* __restrict__ out)
{
  __shared__ char lds[65536];
  const int tid = threadIdx.x;
  const int m0 = blockIdx.x*64;
  const int b = m0 >> 13, l0 = m0 & (LSEQ-1);
  const unsigned short* sF = s2bf + (size_t)b*LSEQ*DI;
  const unsigned short* sB = s2bf + (size_t)(NB + b)*LSEQ*DI;
#pragma unroll
  for (int i = 0; i < 8; ++i) {
    int u = tid + i*512;
    int row = u >> 6, c = u & 63;
    int l = l0 + row;
    const unsigned short* src = (c < 32) ? (sF + (size_t)l*DI + c*8)
                                         : (sB + (size_t)(LSEQ-1-l)*DI + (c-32)*8);
    *(uint4*)(lds + row*1024 + ((c ^ (row & 7))<<4)) = *(const uint4*)src;
  }
  const int wid = tid >> 6;
  const int wr = wid >> 2, wc = wid & 3;
  const int lane = tid & 63, lr = lane & 15, kg = lane >> 4;
  bf16x8 wf[2][8];
#pragma unroll
  for (int nt = 0; nt < 2; ++nt) {
    int n = wc*32 + nt*16 + lr;
#pragma unroll
    for (int kt = 0; kt < 8; ++kt)
      wf[nt][kt] = *(const bf16x8*)(wopbf + n*DI + kt*32 + kg*8);
  }
  __syncthreads();
  f32x4 acc[2][2];
#pragma unroll
  for (int mt = 0; mt < 2; ++mt)
#pragma unroll
    for (int nt = 0; nt < 2; ++nt) acc[mt][nt] = 0.f;
#pragma unroll
  for (int kt2 = 0; kt2 < 16; ++kt2) {
#pragma unroll
    for (int mt = 0; mt < 2; ++mt) {
      int row = wr*32 + mt*16 + lr;
      int slot = (kt2*4 + kg) ^ (row & 7);
      bf16x8 af = *(const bf16x8*)(lds + row*1024 + (slot<<4));
#pragma unroll
      for (int nt = 0; nt < 2; ++nt)
        acc[mt][nt] = __builtin_amdgcn_mfma_f32_16x16x32_bf16(af, wf[nt][kt2 & 7], acc[mt][nt], 0,0,0);
    }
  }
  __syncthreads();
  float* smem = (float*)lds;
  const int RP = 133;
  float* mS = smem + 64*RP;
  float* rS = mS + 64;
  const float* xb = x + b*DM*LSEQ + l0;
#pragma unroll
  for (int mt = 0; mt < 2; ++mt) {
    int mbase = wr*32 + mt*16 + kg*4;
#pragma unroll
    for (int nt = 0; nt < 2; ++nt) {
      int n = wc*32 + nt*16 + lr;
      float4 rx = *(const float4*)&xb[n*LSEQ + mbase];
      smem[(mbase+0)*RP + n] = acc[mt][nt][0] + rx.x;
      smem[(mbase+1)*RP + n] = acc[mt][nt][1] + rx.y;
      smem[(mbase+2)*RP + n] = acc[mt][nt][2] + rx.z;
      smem[(mbase+3)*RP + n] = acc[mt][nt][3] + rx.w;
    }
  }
  __syncthreads();
  {
    int row = tid >> 3, p = tid & 7;
    float s = 0.f, q = 0.f;
#pragma unroll
    for (int jj = 0; jj < 16; ++jj) {
      float v = smem[row*RP + p*16 + jj];
      s += v; q += v*v;
    }
    s += __shfl_xor(s,1); s += __shfl_xor(s,2); s += __shfl_xor(s,4);
    q += __shfl_xor(q,1); q += __shfl_xor(q,2); q += __shfl_xor(q,4);
    if (p == 0) {
      float m = s*(1.f/DM);
      float var = q*(1.f/DM) - m*m;
      mS[row] = m; rS[row] = rsqrtf(var + 1e-5f);
    }
  }
  __syncthreads();
  float* ob = out + b*DM*LSEQ + l0;
#pragma unroll
  for (int i = 0; i < 16; ++i) {
    int idx = tid + i*512;
    int col = idx >> 6, l = idx & 63;
    float v = (smem[l*RP + col] - mS[l])*rS[l]*ln2w[col] + ln2b[col];
    ob[col*LSEQ + l] = v;
  }
}

// ---------------------------------------------------------------------------
extern "C" void kernel_launch(void* const* d_in, const int* in_sizes, int n_in,
                              void* d_out, int out_size, void* d_ws, size_t ws_size,
                              hipStream_t stream)
{
  (void)in_sizes; (void)n_in; (void)out_size; (void)ws_size;
  const float* x     = (const float*)d_in[0];
  const float* ln1w  = (const float*)d_in[1];
  const float* ln1b  = (const float*)d_in[2];
  const float* ln2w  = (const float*)d_in[3];
  const float* ln2b  = (const float*)d_in[4];
  const float* wip   = (const float*)d_in[5];
  const float* wop   = (const float*)d_in[6];
  const float* cwf   = (const float*)d_in[7];
  const float* cbf   = (const float*)d_in[8];
  const float* xwf   = (const float*)d_in[9];
  const float* dtwf  = (const float*)d_in[10];
  const float* dtbf  = (const float*)d_in[11];
  const float* alogf = (const float*)d_in[12];
  const float* Dskf  = (const float*)d_in[13];
  const float* cwb   = (const float*)d_in[14];
  const float* cbb   = (const float*)d_in[15];
  const float* xwb   = (const float*)d_in[16];
  const float* dtwb  = (const float*)d_in[17];
  const float* dtbb  = (const float*)d_in[18];
  const float* alogb = (const float*)d_in[19];
  const float* Dskb  = (const float*)d_in[20];

  // workspace layout (float units) — identical to round 9
  float* ws    = (float*)d_ws;
  float* xibF  = ws;                    //  4,194,304 (xib: 8.4M ushort)
  float* zzbF  = xibF  + 4194304;       //  4,194,304 (zzb: 8.4M ushort)
  float* Bm    = zzbF  + 4194304;       //  1,048,576
  float* Cm    = Bm    + 1048576;       //  1,048,576
  float* s2F   = Cm    + 1048576;       //  8,388,608 (s2bf: 16.8M ushort)
  float* xdtF  = s2F   + 8388608;       // 16,777,216 (packed uint xc|dt)
  float* hlocF = xdtF  + 16777216;      //  4,194,304 (bf16: 8.4M ushort)
  float* sumdt = hlocF + 4194304;       //    524,288
  float* xwbfF = sumdt + 524288;        //     12,288 (24,576 bf16)
  float* wopbfF= xwbfF + 12288;         //     16,384 (32,768 bf16)
  float* out   = (float*)d_out;
  // aliases in s2F region (fully rewritten by k_scan_out each call):
  unsigned short* xnbf  = (unsigned short*)s2F;             // 4,194,304 ush
  unsigned short* wipbf = (unsigned short*)(s2F + 2097152); //    65,536 ush
  unsigned short* s2bf  = (unsigned short*)s2F;
  unsigned short* xib   = (unsigned short*)xibF;
  unsigned short* zzb   = (unsigned short*)zzbF;
  unsigned int*   xdt   = (unsigned int*)xdtF;
  unsigned short* hloc  = (unsigned short*)hlocF;
  unsigned short* xwbf  = (unsigned short*)xwbfF;
  unsigned short* wopbf = (unsigned short*)wopbfF;

  k_prep_w<<<480, 256, 0, stream>>>(wip, wipbf, xwf, xwb, xwbf, wop, wopbf);
  k_ln<<<512, 256, 0, stream>>>(x, ln1w, ln1b, xnbf);
  k_gemm_in<<<512, 256, 0, stream>>>(xnbf, wipbf, xib, zzb);
  k_conv_xproj<<<1024, 256, 0, stream>>>(xib, cwf,cbf,cwb,cbb, xwbf,
                                         dtwf,dtbf,dtwb,dtbb, Bm, Cm, xdt);
  k_scan_local<<<2048, 256, 0, stream>>>(xdt, Bm, alogf, alogb, hloc, sumdt);
  k_prefix<<<512, 64, 0, stream>>>(hloc, sumdt, alogf, alogb);
  k_scan_out<<<2048, 256, 0, stream>>>(xdt, zzb, Bm, Cm, hloc,
                                       alogf, alogb, Dskf, Dskb, s2bf);
  k_out<<<512, 512, 0, stream>>>(s2bf, wopbf, x, ln2w, ln2b, out);
}

// Round 15
// 153.814 us; speedup vs baseline: 1.3495x; 1.0578x over previous
//
#include <hip/hip_runtime.h>

// MambaLayer bidirectional selective-scan — round-9 best configuration.
// bf16 MFMA GEMMs, packed xc/dt scan, packed-fp32 (v_pk_fma_f32) state math.
// Shapes: B=4, L=8192, d_model=128, d_inner=256, d_state=16, dt_rank=8.
#define NB   4
#define LSEQ 8192
#define DM   128
#define DI   256
#define NS   16
#define RK   8
#define NCH  256          // chunks over L
#define LC   32           // L / NCH
#define MTOT (NB*LSEQ)
#define LOG2E 1.44269504088896340736f
#define LN2f  0.69314718055994530942f

#if __has_builtin(__builtin_amdgcn_exp2f)
__device__ __forceinline__ float fexp2(float x){ return __builtin_amdgcn_exp2f(x); }
#else
__device__ __forceinline__ float fexp2(float x){ return exp2f(x); }
#endif
#if __has_builtin(__builtin_amdgcn_logf)
__device__ __forceinline__ float flog2(float x){ return __builtin_amdgcn_logf(x); }
#else
__device__ __forceinline__ float flog2(float x){ return log2f(x); }
#endif
#if __has_builtin(__builtin_amdgcn_rcpf)
__device__ __forceinline__ float frcp(float x){ return __builtin_amdgcn_rcpf(x); }
#else
__device__ __forceinline__ float frcp(float x){ return 1.f/x; }
#endif
__device__ __forceinline__ float fexpn(float x){ return fexp2(x*LOG2E); }
__device__ __forceinline__ float fsilu(float x){ return x*frcp(1.f + fexpn(-x)); }
__device__ __forceinline__ float fsoftplus(float x){
  return fmaxf(x,0.f) + flog2(1.f + fexpn(-fabsf(x)))*LN2f;
}

__device__ __forceinline__ unsigned short f2bf(float v){
  unsigned int u = __float_as_uint(v);
  return (unsigned short)((u + 0x7FFFu + ((u >> 16) & 1u)) >> 16);
}
__device__ __forceinline__ float bf2f(unsigned short h){
  return __uint_as_float(((unsigned int)h) << 16);
}

typedef __attribute__((ext_vector_type(8))) short bf16x8;
typedef __attribute__((ext_vector_type(4))) float f32x4;
typedef __attribute__((ext_vector_type(2))) float f32x2;

#if __has_builtin(__builtin_elementwise_fma)
__device__ __forceinline__ f32x2 pkfma(f32x2 a, f32x2 b, f32x2 c){ return __builtin_elementwise_fma(a,b,c); }
#else
__device__ __forceinline__ f32x2 pkfma(f32x2 a, f32x2 b, f32x2 c){ return a*b + c; }
#endif

// ---------------------------------------------------------------------------
// K0: weights -> bf16: in_proj [512][128]; x_proj padded [2][48][256];
// out_proj [128][256].
// ---------------------------------------------------------------------------
__global__ __launch_bounds__(256) void k_prep_w(
    const float* __restrict__ wip, unsigned short* __restrict__ wipbf,
    const float* __restrict__ xwf, const float* __restrict__ xwb, unsigned short* __restrict__ xwbf,
    const float* __restrict__ wop, unsigned short* __restrict__ wopbf)
{
  int i = blockIdx.x*256 + threadIdx.x;      // 0..122879
  if (i < 65536) {
    wipbf[i] = f2bf(wip[i]);
  } else if (i < 90112) {
    int j = i - 65536;                       // 0..24575
    int dirw = j / 12288;
    int rem = j - dirw*12288;
    int row = rem >> 8, k = rem & 255;
    const float* src = dirw ? xwb : xwf;
    xwbf[j] = (row < 40) ? f2bf(src[row*256 + k]) : (unsigned short)0;
  } else {
    int j = i - 90112;                       // 0..32767
    wopbf[j] = f2bf(wop[j]);
  }
}

// ---------------------------------------------------------------------------
// K1a: LN1 -> xn bf16 [MTOT][128]. Reads x [B,128,L] coalesced.
// ---------------------------------------------------------------------------
__global__ __launch_bounds__(256) void k_ln(
    const float* __restrict__ x, const float* __restrict__ ln1w, const float* __restrict__ ln1b,
    unsigned short* __restrict__ xnbf)
{
  __shared__ float a_s[DM][65];
  __shared__ float mS[64], rS[64];
  const int tid = threadIdx.x;
  const int m0 = blockIdx.x * 64;
  const int b = m0 >> 13, l0 = m0 & (LSEQ-1);
  const float* xb = x + b*DM*LSEQ;
#pragma unroll
  for (int i = 0; i < 32; ++i) {
    int idx = tid + i*256;
    int d = idx >> 6, l = idx & 63;
    a_s[d][l] = xb[d*LSEQ + l0 + l];
  }
  __syncthreads();
  {
    int p = tid & 3, l = tid >> 2;
    float s = 0.f, q = 0.f;
#pragma unroll
    for (int jj = 0; jj < 32; ++jj) {
      float v = a_s[p + 4*jj][l];
      s += v; q += v*v;
    }
    s += __shfl_xor(s,1); s += __shfl_xor(s,2);
    q += __shfl_xor(q,1); q += __shfl_xor(q,2);
    float m = s*(1.f/DM);
    float var = q*(1.f/DM) - m*m;
    if (p == 0) { mS[l] = m; rS[l] = rsqrtf(var + 1e-5f); }
  }
  __syncthreads();
#pragma unroll
  for (int i = 0; i < 32; ++i) {
    int idx = tid + i*256;
    int l = idx >> 7, d = idx & 127;
    float v = (a_s[d][l] - mS[l])*rS[l]*ln1w[d] + ln1b[d];
    xnbf[(m0+l)*DM + d] = f2bf(v);
  }
}

// ---------------------------------------------------------------------------
// K1b: in_proj GEMM via bf16 MFMA (single plane). Tile 64x64, K=128,
// grid (512,8). n0<256 -> xib (bf16); n0>=256 -> zzb = silu(z) bf16
// (silu hoisted here, where the VALU is idle under MFMA).
// ---------------------------------------------------------------------------
__global__ __launch_bounds__(256) void k_gemm_in(
    const unsigned short* __restrict__ xnbf, const unsigned short* __restrict__ wipbf,
    unsigned short* __restrict__ xib, unsigned short* __restrict__ zzb)
{
  __shared__ char lds[32768];                 // 2 planes x 16KB (64 rows x 128 bf16)
  const int tid = threadIdx.x;
  const int m0 = blockIdx.x * 64;
  const int n0 = blockIdx.y * 64;
  const unsigned short* srcs[2] = { xnbf + m0*DM, wipbf + n0*DM };
#pragma unroll
  for (int p = 0; p < 2; ++p) {
#pragma unroll
    for (int i = 0; i < 4; ++i) {
      int u = tid + i*256;                    // 16B unit within plane
      int row = u >> 4, c = u & 15;
      int dstu = p*1024 + row*16 + (c ^ (row & 7));
      *(uint4*)(lds + dstu*16) = *(const uint4*)(srcs[p] + row*DM + c*8);
    }
  }
  __syncthreads();
  const int wid = tid >> 6, lane = tid & 63;
  const int m0w = (wid & 1)*32, n0w = (wid >> 1)*32;
  const int lr = lane & 15, kg = lane >> 4;
  bf16x8 af[2][4], bfv[2][4];
#pragma unroll
  for (int mi = 0; mi < 2; ++mi) {
    int row = m0w + mi*16 + lr;
#pragma unroll
    for (int kk = 0; kk < 4; ++kk) {
      int slot = (kk*4 + kg) ^ (row & 7);
      af[mi][kk] = *(const bf16x8*)(lds + row*256 + slot*16);
    }
  }
#pragma unroll
  for (int nj = 0; nj < 2; ++nj) {
    int row = n0w + nj*16 + lr;
#pragma unroll
    for (int kk = 0; kk < 4; ++kk) {
      int slot = (kk*4 + kg) ^ (row & 7);
      bfv[nj][kk] = *(const bf16x8*)(lds + 16384 + row*256 + slot*16);
    }
  }
  f32x4 acc[2][2];
#pragma unroll
  for (int mi = 0; mi < 2; ++mi)
#pragma unroll
    for (int nj = 0; nj < 2; ++nj) acc[mi][nj] = 0.f;
#pragma unroll
  for (int kk = 0; kk < 4; ++kk)
#pragma unroll
    for (int mi = 0; mi < 2; ++mi)
#pragma unroll
      for (int nj = 0; nj < 2; ++nj)
        acc[mi][nj] = __builtin_amdgcn_mfma_f32_16x16x32_bf16(af[mi][kk], bfv[nj][kk], acc[mi][nj], 0,0,0);
  // C/D: col = lane&15 (n), row = (lane>>4)*4 + r (m)
  if (n0 < 256) {
#pragma unroll
    for (int mi = 0; mi < 2; ++mi)
#pragma unroll
      for (int nj = 0; nj < 2; ++nj) {
        int n_g = n0 + n0w + nj*16 + lr;
#pragma unroll
        for (int r = 0; r < 4; ++r) {
          int m_g = m0 + m0w + mi*16 + kg*4 + r;
          xib[(size_t)m_g*DI + n_g] = f2bf(acc[mi][nj][r]);
        }
      }
  } else {
#pragma unroll
    for (int mi = 0; mi < 2; ++mi)
#pragma unroll
      for (int nj = 0; nj < 2; ++nj) {
        int n_g = (n0 - 256) + n0w + nj*16 + lr;
#pragma unroll
        for (int r = 0; r < 4; ++r) {
          int m_g = m0 + m0w + mi*16 + kg*4 + r;
          zzb[(size_t)m_g*DI + n_g] = f2bf(fsilu(acc[mi][nj][r]));
        }
      }
  }
}

// ---------------------------------------------------------------------------
// K2: conv4+SiLU -> xc into LDS A-plane (phase1); x_proj MFMA (phase2,
// dt_r -> LDS, B/C -> global); phase3: dt = softplus(dt_r@dtw+b), read xc
// back from LDS, ONE packed 4B store per (l,d): lo = xc bf16, hi = dt bf16.
// ---------------------------------------------------------------------------
__global__ __launch_bounds__(256) void k_conv_xproj(
  const unsigned short* __restrict__ xib,
  const float* __restrict__ cwf, const float* __restrict__ cbf,
  const float* __restrict__ cwb, const float* __restrict__ cbb,
  const unsigned short* __restrict__ xwbf,   // [2][48][256] bf16
  const float* __restrict__ dtwf, const float* __restrict__ dtbf,
  const float* __restrict__ dtwb, const float* __restrict__ dtbb,
  float* __restrict__ Bm, float* __restrict__ Cm,
  unsigned int* __restrict__ xdt)
{
  __shared__ char lds[57344];   // A: 64x512B @0; W: 48x512B @32768
  __shared__ float dtr_s[64][8];
  const int tid = threadIdx.x, bid = blockIdx.x;
  const int lt = bid & (LSEQ/64 - 1);
  const int b  = (bid >> 7) & 3;
  const int dir = bid >> 9;
  const int l0 = lt*64;
  const int db = dir*NB + b;
  const unsigned short* xwp = xwbf + dir*48*256;
#pragma unroll
  for (int i = 0; i < 6; ++i) {
    int u = tid + i*256;
    int row = u >> 5, s = u & 31;
    *(uint4*)(lds + 32768 + row*512 + ((s ^ (row & 7))<<4)) =
        *(const uint4*)(xwp + row*256 + s*8);
  }
  const float* cw  = dir ? cwb : cwf;
  const float* cbp = dir ? cbb : cbf;
  const int d = tid;
  const float w0 = cw[d*4+0], w1 = cw[d*4+1], w2 = cw[d*4+2], w3 = cw[d*4+3];
  const float bias = cbp[d];
  const int g0 = dir ? (LSEQ-1-l0) : l0;
  const int stp = dir ? -DI : DI;
  const unsigned short* xp = xib + (size_t)(b*LSEQ)*DI + d + (size_t)g0*DI;
  float h3 = 0.f, h2 = 0.f, h1 = 0.f;
  if (l0 >= 3) { h3 = bf2f(xp[-3*stp]); h2 = bf2f(xp[-2*stp]); h1 = bf2f(xp[-1*stp]); }
  float r0 = bf2f(xp[0]), r1 = bf2f(xp[stp]), r2 = bf2f(xp[2*stp]), r3 = bf2f(xp[3*stp]);
  for (int j = 0; j < 64; j += 4) {
    float v0 = r0, v1 = r1, v2 = r2, v3 = r3;
    if (j + 4 < 64) {
      const unsigned short* q = xp + (j+4)*stp;
      r0 = bf2f(q[0]); r1 = bf2f(q[stp]); r2 = bf2f(q[2*stp]); r3 = bf2f(q[3*stp]);
    }
#pragma unroll
    for (int u = 0; u < 4; ++u) {
      float vv = (u==0)?v0:(u==1)?v1:(u==2)?v2:v3;
      float a = bias + w0*h3 + w1*h2 + w2*h1 + w3*vv;
      int row = j + u;
      *(unsigned short*)(lds + row*512 + ((((d>>3) ^ (row&7))<<4) + ((d&7)<<1))) = f2bf(fsilu(a));
      h3 = h2; h2 = h1; h1 = vv;
    }
  }
  __syncthreads();
  // ---- phase 2: MFMA [64 rows] x [48 cols], K=256 ----
  const int wid = tid >> 6, lane = tid & 63;
  const int lr = lane & 15, kg = lane >> 4;
  const int arow = wid*16 + lr;
  f32x4 acc[3];
#pragma unroll
  for (int j = 0; j < 3; ++j) acc[j] = 0.f;
#pragma unroll
  for (int t = 0; t < 8; ++t) {
    bf16x8 afv = *(const bf16x8*)(lds + arow*512 + (((t*4+kg) ^ (arow&7))<<4));
#pragma unroll
    for (int j = 0; j < 3; ++j) {
      int wrow = j*16 + lr;
      bf16x8 bfr = *(const bf16x8*)(lds + 32768 + wrow*512 + (((t*4+kg) ^ (wrow&7))<<4));
      acc[j] = __builtin_amdgcn_mfma_f32_16x16x32_bf16(afv, bfr, acc[j], 0,0,0);
    }
  }
  const int base_l = (db*LSEQ + l0) + wid*16 + kg*4;
  const int rloc = wid*16 + kg*4;
#pragma unroll
  for (int j = 0; j < 3; ++j) {
    int col = j*16 + lr;
#pragma unroll
    for (int r = 0; r < 4; ++r) {
      float v = acc[j][r];
      if (col < 8)       dtr_s[rloc + r][col] = v;
      else if (col < 24) Bm[(size_t)(base_l + r)*NS + col - 8] = v;
      else if (col < 40) Cm[(size_t)(base_l + r)*NS + col - 24] = v;
    }
  }
  __syncthreads();
  // ---- phase 3: dt = softplus(dtr @ dtw[d] + b[d]); pack with xc (from LDS)
  const float* dtw = dir ? dtwb : dtwf;
  const float* dtbp= dir ? dtbb : dtbf;
  float dwv[8];
  *(float4*)(dwv+0) = *(const float4*)&dtw[d*RK];
  *(float4*)(dwv+4) = *(const float4*)&dtw[d*RK+4];
  const float dtbv = dtbp[d];
  unsigned int* xdtp = xdt + (size_t)(db*LSEQ + l0)*DI + d;
  for (int row = 0; row < 64; ++row) {
    float sd = dtbv;
#pragma unroll
    for (int r = 0; r < RK; ++r) sd = fmaf(dtr_s[row][r], dwv[r], sd);
    unsigned short dtb = f2bf(fsoftplus(sd));
    unsigned short xcb = *(const unsigned short*)(lds + row*512 + ((((d>>3) ^ (row&7))<<4) + ((d&7)<<1)));
    xdtp[(size_t)row*DI] = (unsigned int)xcb | ((unsigned int)dtb << 16);
  }
}

// ---------------------------------------------------------------------------
// K3: chunk-local scan from h=0 -> h_local (bf16) + sum(dt).
// Packed-fp32 state math (f32x2 -> v_pk_fma_f32), LDS B staging.
// ---------------------------------------------------------------------------
__global__ __launch_bounds__(256) void k_scan_local(
  const unsigned int* __restrict__ xdt, const float* __restrict__ Bm,
  const float* __restrict__ alogf, const float* __restrict__ alogb,
  unsigned short* __restrict__ hloc, float* __restrict__ sumdt)
{
  __shared__ float Bc[LC][NS];
  const int tid = threadIdx.x, bid = blockIdx.x;
  const int c = bid & (NCH-1), b = (bid>>8)&3, dir = bid>>10;
  const int db = dir*NB + b;
  const int l0 = c*LC;
  for (int i = tid; i < LC*NS; i += 256) (&Bc[0][0])[i] = Bm[(size_t)(db*LSEQ + l0)*NS + i];
  const float* alog = dir ? alogb : alogf;
  const int d = tid;
  float A2[NS];
#pragma unroll
  for (int n = 0; n < NS; ++n) A2[n] = -fexpn(alog[d*NS+n]) * LOG2E;
  const float a20 = A2[0];
  bool pw = true;
#pragma unroll
  for (int n = 1; n < NS; ++n) pw = pw && (fabsf(A2[n] - (n+1)*a20) <= 1e-3f*fabsf(A2[n]));
  f32x2 h2[8];
#pragma unroll
  for (int k = 0; k < 8; ++k) h2[k] = 0.f;
  const unsigned int* xp = xdt + (size_t)(db*LSEQ + l0)*DI + d;
  unsigned int u0 = xp[0], u1 = xp[DI], u2 = xp[2*DI], u3 = xp[3*DI];
  __syncthreads();
  float sac = 0.f;
  for (int j = 0; j < LC; j += 4) {
    unsigned int w0=u0, w1=u1, w2=u2, w3=u3;
    if (j + 4 < LC) {
      const unsigned int* q = xp + (size_t)(j+4)*DI;
      u0=q[0]; u1=q[DI]; u2=q[2*DI]; u3=q[3*DI];
    }
#pragma unroll
    for (int u = 0; u < 4; ++u) {
      unsigned int uu = (u==0)?w0:(u==1)?w1:(u==2)?w2:w3;
      float xc = __uint_as_float(uu << 16);
      float dt = __uint_as_float(uu & 0xffff0000u);
      sac += dt;
      float dx = dt*xc;
      f32x2 e2[8];
      if (pw) {
        float e1 = fexp2(a20*dt);
        float es = e1*e1;
        f32x2 esq = {es, es};
        e2[0] = (f32x2){e1, es};
#pragma unroll
        for (int k = 1; k < 8; ++k) e2[k] = e2[k-1]*esq;
      } else {
#pragma unroll
        for (int k = 0; k < 8; ++k)
          e2[k] = (f32x2){fexp2(A2[2*k]*dt), fexp2(A2[2*k+1]*dt)};
      }
      const f32x2* bb2 = (const f32x2*)&Bc[j+u][0];
      f32x2 dx2 = {dx, dx};
#pragma unroll
      for (int k = 0; k < 8; ++k) h2[k] = pkfma(h2[k], e2[k], bb2[k]*dx2);
    }
  }
  // pack h -> bf16, 32B store
  unsigned int hp8[8];
#pragma unroll
  for (int k = 0; k < 8; ++k)
    hp8[k] = (unsigned int)f2bf(h2[k].x) | ((unsigned int)f2bf(h2[k].y) << 16);
  unsigned short* dst = hloc + ((size_t)(db*NCH + c)*DI + d)*NS;
  *(uint4*)(dst)   = *(uint4*)(hp8);
  *(uint4*)(dst+8) = *(uint4*)(hp8+4);
  sumdt[(size_t)(db*NCH + c)*DI + d] = sac;
}

// ---------------------------------------------------------------------------
// K4: sequential prefix over chunks (bf16 h, fp32 carry), 16-deep prefetch,
// IN-PLACE: hloc[c] becomes h_in[c].
// ---------------------------------------------------------------------------
__global__ __launch_bounds__(64) void k_prefix(
  unsigned short* __restrict__ hloc, const float* __restrict__ sumdt,
  const float* __restrict__ alogf, const float* __restrict__ alogb)
{
  const int gid = blockIdx.x*64 + threadIdx.x;   // 32768
  const int n = gid & 15;
  const int d = (gid >> 4) & 255;
  const int db = gid >> 12;
  const float* alog = (db >= NB) ? alogb : alogf;
  const float a2 = -fexpn(alog[d*NS+n]) * LOG2E;
  const int HS = DI*NS;                          // per-chunk stride (ushorts)
  unsigned short* hp = hloc + (size_t)db*NCH*HS + d*NS + n;
  const float* sp = sumdt + (size_t)db*NCH*DI + d;
  float hr = 0.f;
  float bl[16], bs[16];
#pragma unroll
  for (int j = 0; j < 16; ++j) { bl[j] = bf2f(hp[(size_t)j*HS]); bs[j] = sp[(size_t)j*DI]; }
  for (int blk = 0; blk < NCH/16; ++blk) {
    float nl[16], nsv[16];
    if (blk < NCH/16 - 1) {
#pragma unroll
      for (int j = 0; j < 16; ++j) {
        nl[j]  = bf2f(hp[(size_t)(blk*16+16+j)*HS]);
        nsv[j] = sp[(size_t)(blk*16+16+j)*DI];
      }
    }
#pragma unroll
    for (int j = 0; j < 16; ++j) {
      float hl = bl[j];
      hp[(size_t)(blk*16+j)*HS] = f2bf(hr);
      hr = fmaf(fexp2(a2*bs[j]), hr, hl);
    }
    if (blk < NCH/16 - 1) {
#pragma unroll
      for (int j = 0; j < 16; ++j) { bl[j] = nl[j]; bs[j] = nsv[j]; }
    }
  }
}

// ---------------------------------------------------------------------------
// K5: rescan from h_in producing y, + D-skip, * pre-silu'd z -> s (bf16).
// Packed-fp32 state math, LDS B/C staging.
// ---------------------------------------------------------------------------
__global__ __launch_bounds__(256) void k_scan_out(
  const unsigned int* __restrict__ xdt, const unsigned short* __restrict__ zzb,
  const float* __restrict__ Bm, const float* __restrict__ Cm,
  const unsigned short* __restrict__ hinb,
  const float* __restrict__ alogf, const float* __restrict__ alogb,
  const float* __restrict__ Dskf, const float* __restrict__ Dskb,
  unsigned short* __restrict__ s2bf)
{
  __shared__ float Bc[LC][NS];
  __shared__ float Cc[LC][NS];
  const int tid = threadIdx.x, bid = blockIdx.x;
  const int c = bid & (NCH-1), b = (bid>>8)&3, dir = bid>>10;
  const int db = dir*NB + b;
  const int l0 = c*LC;
  for (int i = tid; i < LC*NS; i += 256) (&Bc[0][0])[i] = Bm[(size_t)(db*LSEQ + l0)*NS + i];
  for (int i = tid; i < LC*NS; i += 256) (&Cc[0][0])[i] = Cm[(size_t)(db*LSEQ + l0)*NS + i];
  const float* alog = dir ? alogb : alogf;
  const int d = tid;
  const float Dd = (dir ? Dskb : Dskf)[d];
  float A2[NS];
#pragma unroll
  for (int n = 0; n < NS; ++n) A2[n] = -fexpn(alog[d*NS+n]) * LOG2E;
  const float a20 = A2[0];
  bool pw = true;
#pragma unroll
  for (int n = 1; n < NS; ++n) pw = pw && (fabsf(A2[n] - (n+1)*a20) <= 1e-3f*fabsf(A2[n]));
  // h_in (bf16 -> fp32)
  f32x2 h2[8];
  {
    const unsigned short* hb = hinb + ((size_t)(db*NCH + c)*DI + d)*NS;
    uint4 p0 = *(const uint4*)(hb);
    uint4 p1 = *(const uint4*)(hb+8);
    unsigned int w[8] = {p0.x,p0.y,p0.z,p0.w,p1.x,p1.y,p1.z,p1.w};
#pragma unroll
    for (int k = 0; k < 8; ++k)
      h2[k] = (f32x2){__uint_as_float(w[k] << 16), __uint_as_float(w[k] & 0xffff0000u)};
  }
  const int g0 = dir ? (LSEQ-1-l0) : l0;
  const int stp = dir ? -DI : DI;
  const unsigned int* xp = xdt + (size_t)(db*LSEQ + l0)*DI + d;
  const unsigned short* zp = zzb + (size_t)(b*LSEQ + g0)*DI + d;
  unsigned short* sp = s2bf + (size_t)(db*LSEQ + l0)*DI + d;
  unsigned int u0 = xp[0], u1 = xp[DI], u2 = xp[2*DI], u3 = xp[3*DI];
  unsigned short z0 = zp[0], z1 = zp[stp], z2 = zp[2*stp], z3 = zp[3*stp];
  __syncthreads();
  for (int j = 0; j < LC; j += 4) {
    unsigned int w0=u0, w1=u1, w2=u2, w3=u3;
    unsigned short y0=z0, y1=z1, y2=z2, y3=z3;
    if (j + 4 < LC) {
      const unsigned int* q = xp + (size_t)(j+4)*DI;
      u0=q[0]; u1=q[DI]; u2=q[2*DI]; u3=q[3*DI];
      const unsigned short* qz = zp + (j+4)*stp;
      z0=qz[0]; z1=qz[stp]; z2=qz[2*stp]; z3=qz[3*stp];
    }
#pragma unroll
    for (int u = 0; u < 4; ++u) {
      unsigned int uu = (u==0)?w0:(u==1)?w1:(u==2)?w2:w3;
      unsigned short zu = (u==0)?y0:(u==1)?y1:(u==2)?y2:y3;
      float xc = __uint_as_float(uu << 16);
      float dt = __uint_as_float(uu & 0xffff0000u);
      float dx = dt*xc;
      f32x2 e2[8];
      if (pw) {
        float e1 = fexp2(a20*dt);
        float es = e1*e1;
        f32x2 esq = {es, es};
        e2[0] = (f32x2){e1, es};
#pragma unroll
        for (int k = 1; k < 8; ++k) e2[k] = e2[k-1]*esq;
      } else {
#pragma unroll
        for (int k = 0; k < 8; ++k)
          e2[k] = (f32x2){fexp2(A2[2*k]*dt), fexp2(A2[2*k+1]*dt)};
      }
      const f32x2* bb2 = (const f32x2*)&Bc[j+u][0];
      const f32x2* cc2 = (const f32x2*)&Cc[j+u][0];
      f32x2 dx2 = {dx, dx};
      f32x2 yv2 = {0.f, 0.f};
#pragma unroll
      for (int k = 0; k < 8; ++k) {
        h2[k] = pkfma(h2[k], e2[k], bb2[k]*dx2);
        yv2 = pkfma(h2[k], cc2[k], yv2);
      }
      float yv = yv2.x + yv2.y;
      yv = fmaf(xc, Dd, yv);
      sp[(size_t)(j+u)*DI] = f2bf(yv * bf2f(zu));   // z pre-silu'd in k_gemm_in
    }
  }
}

// ---------------------------------------------------------------------------
// K6: MFMA out_proj. (sF + rev(sB)) @ W^T == [sF | rev(sB)] @ [W;W]^T.
// Epilogue: +residual, LN2, transposed store.
// ---------------------------------------------------------------------------
__global__ __launch_bounds__(512) void k_out(
  const unsigned short* __restrict__ s2bf,  // [2][NB][LSEQ][DI] bf16
  const unsigned short* __restrict__ wopbf, // [DM][DI] bf16
  const float* __restrict__ x, const float* __restrict__ ln2w, const float* __restrict__ ln2b,
  float* __restrict__ out)
{
  __shared__ char lds[65536];
  const int tid = threadIdx.x;
  const int m0 = blockIdx.x*64;
  const int b = m0 >> 13, l0 = m0 & (LSEQ-1);
  const unsigned short* sF = s2bf + (size_t)b*LSEQ*DI;
  const unsigned short* sB = s2bf + (size_t)(NB + b)*LSEQ*DI;
#pragma unroll
  for (int i = 0; i < 8; ++i) {
    int u = tid + i*512;
    int row = u >> 6, c = u & 63;
    int l = l0 + row;
    const unsigned short* src = (c < 32) ? (sF + (size_t)l*DI + c*8)
                                         : (sB + (size_t)(LSEQ-1-l)*DI + (c-32)*8);
    *(uint4*)(lds + row*1024 + ((c ^ (row & 7))<<4)) = *(const uint4*)src;
  }
  const int wid = tid >> 6;
  const int wr = wid >> 2, wc = wid & 3;
  const int lane = tid & 63, lr = lane & 15, kg = lane >> 4;
  bf16x8 wf[2][8];
#pragma unroll
  for (int nt = 0; nt < 2; ++nt) {
    int n = wc*32 + nt*16 + lr;
#pragma unroll
    for (int kt = 0; kt < 8; ++kt)
      wf[nt][kt] = *(const bf16x8*)(wopbf + n*DI + kt*32 + kg*8);
  }
  __syncthreads();
  f32x4 acc[2][2];
#pragma unroll
  for (int mt = 0; mt < 2; ++mt)
#pragma unroll
    for (int nt = 0; nt < 2; ++nt) acc[mt][nt] = 0.f;
#pragma unroll
  for (int kt2 = 0; kt2 < 16; ++kt2) {
#pragma unroll
    for (int mt = 0; mt < 2; ++mt) {
      int row = wr*32 + mt*16 + lr;
      int slot = (kt2*4 + kg) ^ (row & 7);
      bf16x8 af = *(const bf16x8*)(lds + row*1024 + (slot<<4));
#pragma unroll
      for (int nt = 0; nt < 2; ++nt)
        acc[mt][nt] = __builtin_amdgcn_mfma_f32_16x16x32_bf16(af, wf[nt][kt2 & 7], acc[mt][nt], 0,0,0);
    }
  }
  __syncthreads();
  float* smem = (float*)lds;
  const int RP = 133;
  float* mS = smem + 64*RP;
  float* rS = mS + 64;
  const float* xb = x + b*DM*LSEQ + l0;
#pragma unroll
  for (int mt = 0; mt < 2; ++mt) {
    int mbase = wr*32 + mt*16 + kg*4;
#pragma unroll
    for (int nt = 0; nt < 2; ++nt) {
      int n = wc*32 + nt*16 + lr;
      float4 rx = *(const float4*)&xb[n*LSEQ + mbase];
      smem[(mbase+0)*RP + n] = acc[mt][nt][0] + rx.x;
      smem[(mbase+1)*RP + n] = acc[mt][nt][1] + rx.y;
      smem[(mbase+2)*RP + n] = acc[mt][nt][2] + rx.z;
      smem[(mbase+3)*RP + n] = acc[mt][nt][3] + rx.w;
    }
  }
  __syncthreads();
  {
    int row = tid >> 3, p = tid & 7;
    float s = 0.f, q = 0.f;
#pragma unroll
    for (int jj = 0; jj < 16; ++jj) {
      float v = smem[row*RP + p*16 + jj];
      s += v; q += v*v;
    }
    s += __shfl_xor(s,1); s += __shfl_xor(s,2); s += __shfl_xor(s,4);
    q += __shfl_xor(q,1); q += __shfl_xor(q,2); q += __shfl_xor(q,4);
    if (p == 0) {
      float m = s*(1.f/DM);
      float var = q*(1.f/DM) - m*m;
      mS[row] = m; rS[row] = rsqrtf(var + 1e-5f);
    }
  }
  __syncthreads();
  float* ob = out + b*DM*LSEQ + l0;
#pragma unroll
  for (int i = 0; i < 16; ++i) {
    int idx = tid + i*512;
    int col = idx >> 6, l = idx & 63;
    float v = (smem[l*RP + col] - mS[l])*rS[l]*ln2w[col] + ln2b[col];
    ob[col*LSEQ + l] = v;
  }
}

// ---------------------------------------------------------------------------
extern "C" void kernel_launch(void* const* d_in, const int* in_sizes, int n_in,
                              void* d_out, int out_size, void* d_ws, size_t ws_size,
                              hipStream_t stream)
{
  (void)in_sizes; (void)n_in; (void)out_size; (void)ws_size;
  const float* x     = (const float*)d_in[0];
  const float* ln1w  = (const float*)d_in[1];
  const float* ln1b  = (const float*)d_in[2];
  const float* ln2w  = (const float*)d_in[3];
  const float* ln2b  = (const float*)d_in[4];
  const float* wip   = (const float*)d_in[5];
  const float* wop   = (const float*)d_in[6];
  const float* cwf   = (const float*)d_in[7];
  const float* cbf   = (const float*)d_in[8];
  const float* xwf   = (const float*)d_in[9];
  const float* dtwf  = (const float*)d_in[10];
  const float* dtbf  = (const float*)d_in[11];
  const float* alogf = (const float*)d_in[12];
  const float* Dskf  = (const float*)d_in[13];
  const float* cwb   = (const float*)d_in[14];
  const float* cbb   = (const float*)d_in[15];
  const float* xwb   = (const float*)d_in[16];
  const float* dtwb  = (const float*)d_in[17];
  const float* dtbb  = (const float*)d_in[18];
  const float* alogb = (const float*)d_in[19];
  const float* Dskb  = (const float*)d_in[20];

  // workspace layout (float units) — identical to round 9
  float* ws    = (float*)d_ws;
  float* xibF  = ws;                    //  4,194,304 (xib: 8.4M ushort)
  float* zzbF  = xibF  + 4194304;       //  4,194,304 (zzb: 8.4M ushort)
  float* Bm    = zzbF  + 4194304;       //  1,048,576
  float* Cm    = Bm    + 1048576;       //  1,048,576
  float* s2F   = Cm    + 1048576;       //  8,388,608 (s2bf: 16.8M ushort)
  float* xdtF  = s2F   + 8388608;       // 16,777,216 (packed uint xc|dt)
  float* hlocF = xdtF  + 16777216;      //  4,194,304 (bf16: 8.4M ushort)
  float* sumdt = hlocF + 4194304;       //    524,288
  float* xwbfF = sumdt + 524288;        //     12,288 (24,576 bf16)
  float* wopbfF= xwbfF + 12288;         //     16,384 (32,768 bf16)
  float* out   = (float*)d_out;
  // aliases in s2F region (fully rewritten by k_scan_out each call):
  unsigned short* xnbf  = (unsigned short*)s2F;             // 4,194,304 ush
  unsigned short* wipbf = (unsigned short*)(s2F + 2097152); //    65,536 ush
  unsigned short* s2bf  = (unsigned short*)s2F;
  unsigned short* xib   = (unsigned short*)xibF;
  unsigned short* zzb   = (unsigned short*)zzbF;
  unsigned int*   xdt   = (unsigned int*)xdtF;
  unsigned short* hloc  = (unsigned short*)hlocF;
  unsigned short* xwbf  = (unsigned short*)xwbfF;
  unsigned short* wopbf = (unsigned short*)wopbfF;

  k_prep_w<<<480, 256, 0, stream>>>(wip, wipbf, xwf, xwb, xwbf, wop, wopbf);
  k_ln<<<512, 256, 0, stream>>>(x, ln1w, ln1b, xnbf);
  k_gemm_in<<<dim3(512,8), 256, 0, stream>>>(xnbf, wipbf, xib, zzb);
  k_conv_xproj<<<1024, 256, 0, stream>>>(xib, cwf,cbf,cwb,cbb, xwbf,
                                         dtwf,dtbf,dtwb,dtbb, Bm, Cm, xdt);
  k_scan_local<<<2048, 256, 0, stream>>>(xdt, Bm, alogf, alogb, hloc, sumdt);
  k_prefix<<<512, 64, 0, stream>>>(hloc, sumdt, alogf, alogb);
  k_scan_out<<<2048, 256, 0, stream>>>(xdt, zzb, Bm, Cm, hloc,
                                       alogf, alogb, Dskf, Dskb, s2bf);
  k_out<<<512, 512, 0, stream>>>(s2bf, wopbf, x, ln2w, ln2b, out);
}